// Round 1
// baseline (409.217 us; speedup 1.0000x reference)
//
#include <hip/hip_runtime.h>
#include <math.h>

// Problem constants
#define N_A   1024
#define HDIM  128
#define DIN   172
#define E_CNT 256

// Gauss-Legendre nodes/weights mapped to [0,1] (tau=1)
__constant__ float c_t[8] = {
    0.4082826787521751f, 0.2372337950418355f, 0.10166676129318665f, 0.019855071751231843f,
    0.5917173212478249f, 0.7627662049581645f, 0.8983332387068134f, 0.9801449282487682f};
__constant__ float c_w[8] = {
    0.181341891689181f, 0.15685332293894365f, 0.11119051722668725f, 0.05061426814518815f,
    0.181341891689181f, 0.15685332293894365f, 0.11119051722668725f, 0.05061426814518815f};

// ---------------------------------------------------------------------------
// zt = [x_sub | neigh] @ W_tune + b_tune      (per-row kernel, K=174)
// ---------------------------------------------------------------------------
__global__ __launch_bounds__(128)
void ew_zt(const float* __restrict__ x_sub, const float* __restrict__ names,
           const int* __restrict__ src, const int* __restrict__ dst,
           const float* __restrict__ W_tune, const float* __restrict__ b_tune,
           float* __restrict__ zt)
{
    const int i = blockIdx.x, j = threadIdx.x;
    __shared__ float xl[DIN + 2];
    for (int k = j; k < DIN; k += 128) xl[k] = x_sub[(size_t)i * DIN + k];
    if (j == 0) {
        float n0 = 0.f, n1 = 0.f;
        if (i < E_CNT)            { n0 = names[src[i]];          n1 = names[dst[i]]; }
        else if (i < 2 * E_CNT)   { n0 = names[dst[i - E_CNT]];  n1 = names[src[i - E_CNT]]; }
        xl[DIN] = n0; xl[DIN + 1] = n1;
    }
    __syncthreads();
    float acc = b_tune[j];
    #pragma unroll 2
    for (int k = 0; k < DIN + 2; ++k) acc += xl[k] * W_tune[k * HDIM + j];
    zt[(size_t)i * HDIM + j] = acc;
}

// ---------------------------------------------------------------------------
// Per-row pre kernel: (optional u2 = zt + gelu(uc_prev)), rmsnorm, delta
// (softplus), Bz = xn@W_B + b_B, V = Bz*delta, U = m_gather * exp(dA)
// ---------------------------------------------------------------------------
__global__ __launch_bounds__(128)
void ew_pre(const float* __restrict__ zt, const float* __restrict__ uc_prev,
            const float* __restrict__ rms_scale, const float* __restrict__ W_B,
            const float* __restrict__ b_B, const float* __restrict__ W_dt,
            const float* __restrict__ b_dt, const float* __restrict__ A_log,
            const float* __restrict__ m_vec, const int* __restrict__ act_ids,
            float* __restrict__ V, float* __restrict__ U, float* __restrict__ dlt)
{
    const int i = blockIdx.x, j = threadIdx.x;
    __shared__ float xs[HDIM];
    __shared__ float red[HDIM];

    float x = zt[(size_t)i * HDIM + j];
    if (uc_prev) {
        float g = uc_prev[(size_t)i * HDIM + j];
        float g3 = g * g * g;
        x += 0.5f * g * (1.0f + tanhf(0.7978845608028654f * (g + 0.044715f * g3)));
    }
    red[j] = x * x;
    __syncthreads();
    #pragma unroll
    for (int s = 64; s > 0; s >>= 1) { if (j < s) red[j] += red[j + s]; __syncthreads(); }
    const float rms = sqrtf(red[0]) * 0.08838834764831845f;  // /sqrt(128)
    const float xn = rms_scale[j] * x / (rms + 1e-8f);
    xs[j] = xn;
    __syncthreads();                      // everyone done reading red[0]
    red[j] = xn * W_dt[j];
    __syncthreads();
    #pragma unroll
    for (int s = 64; s > 0; s >>= 1) { if (j < s) red[j] += red[j + s]; __syncthreads(); }
    const float dd = red[0] + b_dt[0];
    const float delta = dd > 0.f ? dd + log1pf(expf(-dd)) : log1pf(expf(dd));

    float acc = b_B[j];
    #pragma unroll 8
    for (int k = 0; k < HDIM; ++k) acc += xs[k] * W_B[k * HDIM + j];

    V[(size_t)i * HDIM + j] = acc * delta;
    const int aid = act_ids[i];
    U[(size_t)i * HDIM + j] = m_vec[(size_t)aid * HDIM + j] * expf(-delta * expf(A_log[j]));
    if (j == 0) dlt[i] = delta;
}

// ---------------------------------------------------------------------------
// fp32 GEMM, K=1024 fixed. C[M x N] = alpha*(A @ B) + beta*D
// A rows: r < 1024 -> A0, else A1 (stacked).  Rows >=1024 write at C+coff1.
// Tile 64x64, BK=32, 256 threads, 4x4 microtile.
// grid = (N/64, M/64)
// ---------------------------------------------------------------------------
#define GBK 32
__global__ __launch_bounds__(256)
void gemm_k1024(const float* __restrict__ A0, const float* __restrict__ A1,
                const float* __restrict__ B, int ldb,
                float* __restrict__ C, int ldc, int coff1,
                float alpha, const float* __restrict__ D, int ldd, float beta)
{
    __shared__ float As[GBK][68];   // transposed [k][r], padded to kill bank conflicts
    __shared__ float Bs[GBK][64];

    const int tid = threadIdx.x;
    const int rb = blockIdx.y, cb = blockIdx.x;
    const float* A = (rb < 16) ? (A0 + (size_t)rb * 64 * 1024)
                               : (A1 + (size_t)(rb - 16) * 64 * 1024);
    const int crow0 = (rb < 16) ? rb * 64 : (rb - 16) * 64;
    float* Cb = C + ((rb < 16) ? 0 : coff1);
    const int col0 = cb * 64;

    const int ar = tid >> 2;            // 0..63
    const int ac = (tid & 3) << 2;      // 0,4,8,12
    const int bk = tid >> 3;            // 0..31
    const int bc = (tid & 7) << 2;      // 0..28

    const int ty = tid >> 4, tx = tid & 15;
    float acc[4][4] = {};

    for (int k0 = 0; k0 < 1024; k0 += GBK) {
        const float* arow = A + (size_t)ar * 1024 + k0;
        float4 a0 = *(const float4*)(arow + ac);
        float4 a1 = *(const float4*)(arow + ac + 16);
        const float* brow0 = B + (size_t)(k0 + bk) * ldb + col0;
        float4 b0 = *(const float4*)(brow0 + bc);
        float4 b1 = *(const float4*)(brow0 + bc + 32);
        __syncthreads();
        As[ac + 0][ar] = a0.x; As[ac + 1][ar] = a0.y;
        As[ac + 2][ar] = a0.z; As[ac + 3][ar] = a0.w;
        As[ac + 16][ar] = a1.x; As[ac + 17][ar] = a1.y;
        As[ac + 18][ar] = a1.z; As[ac + 19][ar] = a1.w;
        *(float4*)&Bs[bk][bc] = b0;
        *(float4*)&Bs[bk][bc + 32] = b1;
        __syncthreads();
        #pragma unroll
        for (int kk = 0; kk < GBK; ++kk) {
            float4 av = *(const float4*)&As[kk][ty * 4];
            float4 bv = *(const float4*)&Bs[kk][tx * 4];
            acc[0][0] += av.x * bv.x; acc[0][1] += av.x * bv.y;
            acc[0][2] += av.x * bv.z; acc[0][3] += av.x * bv.w;
            acc[1][0] += av.y * bv.x; acc[1][1] += av.y * bv.y;
            acc[1][2] += av.y * bv.z; acc[1][3] += av.y * bv.w;
            acc[2][0] += av.z * bv.x; acc[2][1] += av.z * bv.y;
            acc[2][2] += av.z * bv.z; acc[2][3] += av.z * bv.w;
            acc[3][0] += av.w * bv.x; acc[3][1] += av.w * bv.y;
            acc[3][2] += av.w * bv.z; acc[3][3] += av.w * bv.w;
        }
    }

    #pragma unroll
    for (int ii = 0; ii < 4; ++ii) {
        const int r = crow0 + ty * 4 + ii;
        float* crow = Cb + (size_t)r * ldc + col0 + tx * 4;
        float4 v;
        v.x = alpha * acc[ii][0]; v.y = alpha * acc[ii][1];
        v.z = alpha * acc[ii][2]; v.w = alpha * acc[ii][3];
        if (D) {
            const float* drow = D + (size_t)r * ldd + col0 + tx * 4;
            v.x += beta * drow[0]; v.y += beta * drow[1];
            v.z += beta * drow[2]; v.w += beta * drow[3];
        }
        *(float4*)crow = v;
    }
}

// ---------------------------------------------------------------------------
// Final combine: out = U - 0.1 Q + 0.01 R2 + 0.005 R3
//                    + sum_k w_k (G + t_k(-0.1 Y1 + 0.01 Y2) + 0.005 t_k^2 Y3) e^{dA t_k}
// BIG layout cols: [H | Y1 | P | Q]; YR layout cols: [Y2 | Y3 | R2 | R3]
// ---------------------------------------------------------------------------
__global__ __launch_bounds__(256)
void ew_post(const float* __restrict__ G, const float* __restrict__ BIG,
             const float* __restrict__ YR, const float* __restrict__ U,
             const float* __restrict__ dlt, const float* __restrict__ A_log,
             float* __restrict__ out)
{
    const int idx = blockIdx.x * 256 + threadIdx.x;   // 131072 elements
    const int i = idx >> 7, j = idx & 127;
    const float dA = -dlt[i] * expf(A_log[j]);
    const float g  = G[idx];
    const size_t rb = (size_t)i * 512;
    const float y1 = BIG[rb + 128 + j];
    const float q  = BIG[rb + 384 + j];
    const float y2 = YR[rb + j];
    const float y3 = YR[rb + 128 + j];
    const float r2 = YR[rb + 256 + j];
    const float r3 = YR[rb + 384 + j];
    const float bl = -0.1f * y1 + 0.01f * y2;
    const float cq = 0.005f * y3;
    float integ = 0.f;
    #pragma unroll
    for (int k = 0; k < 8; ++k) {
        const float t = c_t[k];
        integ += c_w[k] * (g + t * bl + t * t * cq) * expf(dA * t);
    }
    out[idx] = U[idx] - 0.1f * q + 0.01f * r2 + 0.005f * r3 + integ;
}

// ---------------------------------------------------------------------------
extern "C" void kernel_launch(void* const* d_in, const int* in_sizes, int n_in,
                              void* d_out, int out_size, void* d_ws, size_t ws_size,
                              hipStream_t stream)
{
    const float* L      = (const float*)d_in[0];
    const float* dL     = (const float*)d_in[1];
    const float* x_sub  = (const float*)d_in[2];
    const float* m1     = (const float*)d_in[3];
    const float* m2     = (const float*)d_in[4];
    const float* names  = (const float*)d_in[5];
    const float* rms1   = (const float*)d_in[6];
    const float* rms2   = (const float*)d_in[7];
    const float* W_tune = (const float*)d_in[8];
    const float* b_tune = (const float*)d_in[9];
    const float* W_B1   = (const float*)d_in[10];
    const float* b_B1   = (const float*)d_in[11];
    const float* W_B2   = (const float*)d_in[12];
    const float* b_B2   = (const float*)d_in[13];
    const float* W_dt   = (const float*)d_in[14];
    const float* b_dt   = (const float*)d_in[15];
    const float* A1     = (const float*)d_in[16];
    const float* A2     = (const float*)d_in[17];
    const int*   src    = (const int*)d_in[18];
    const int*   dst    = (const int*)d_in[19];
    const int*   act    = (const int*)d_in[20];
    float* out = (float*)d_out;

    // Workspace layout (floats). Needs ~6.3 MB.
    float* ws   = (float*)d_ws;
    float* zt   = ws;                    // 1024*128
    float* V    = zt + 131072;           // 1024*128
    float* U    = V  + 131072;           // 1024*128
    float* G    = U  + 131072;           // 1024*128
    float* BIG  = G  + 131072;           // 1024*512  [H|Y1|P|Q]
    float* YR   = BIG + 524288;          // 1024*512  [Y2|Y3|R2|R3]
    float* dlt  = YR + 524288;           // 1024

    ew_zt<<<dim3(1024), dim3(128), 0, stream>>>(x_sub, names, src, dst, W_tune, b_tune, zt);

    for (int s = 0; s < 2; ++s) {
        ew_pre<<<dim3(1024), dim3(128), 0, stream>>>(
            zt, s ? out : nullptr,
            s ? rms2 : rms1, s ? W_B2 : W_B1, s ? b_B2 : b_B1,
            W_dt, b_dt, s ? A2 : A1, s ? m2 : m1, act, V, U, dlt);

        // G = V - 0.1 * (L @ V)
        gemm_k1024<<<dim3(2, 16), dim3(256), 0, stream>>>(
            L, L, V, HDIM, G, HDIM, 0, -0.1f, V, HDIM, 1.0f);
        // [P;Q] = [L;dL] @ U   -> BIG cols 256:512
        gemm_k1024<<<dim3(2, 32), dim3(256), 0, stream>>>(
            L, dL, U, HDIM, BIG + 256, 512, 128, 1.0f, nullptr, 0, 0.f);
        // [H;Y1] = [L;dL] @ G  -> BIG cols 0:256
        gemm_k1024<<<dim3(2, 32), dim3(256), 0, stream>>>(
            L, dL, G, HDIM, BIG, 512, 128, 1.0f, nullptr, 0, 0.f);
        // [Y2|Y3|R2|R3] = dL @ [H|Y1|P|Q]
        gemm_k1024<<<dim3(8, 16), dim3(256), 0, stream>>>(
            dL, dL, BIG, 512, YR, 512, 0, 1.0f, nullptr, 0, 0.f);

        ew_post<<<dim3(512), dim3(256), 0, stream>>>(
            G, BIG, YR, U, dlt, s ? A2 : A1, out + (size_t)s * 131072);
    }
}

// Round 2
// 191.470 us; speedup vs baseline: 2.1372x; 2.1372x over previous
//
#include <hip/hip_runtime.h>
#include <math.h>

// Problem constants
#define N_A   1024
#define HDIM  128
#define DIN   172
#define E_CNT 256

// Gauss-Legendre nodes/weights mapped to [0,1] (tau=1)
__constant__ float c_t[8] = {
    0.4082826787521751f, 0.2372337950418355f, 0.10166676129318665f, 0.019855071751231843f,
    0.5917173212478249f, 0.7627662049581645f, 0.8983332387068134f, 0.9801449282487682f};
__constant__ float c_w[8] = {
    0.181341891689181f, 0.15685332293894365f, 0.11119051722668725f, 0.05061426814518815f,
    0.181341891689181f, 0.15685332293894365f, 0.11119051722668725f, 0.05061426814518815f};

// ---------------------------------------------------------------------------
// zt = [x_sub | neigh] @ W_tune + b_tune      (per-row kernel, K=174)
// ---------------------------------------------------------------------------
__global__ __launch_bounds__(128)
void ew_zt(const float* __restrict__ x_sub, const float* __restrict__ names,
           const int* __restrict__ src, const int* __restrict__ dst,
           const float* __restrict__ W_tune, const float* __restrict__ b_tune,
           float* __restrict__ zt)
{
    const int i = blockIdx.x, j = threadIdx.x;
    __shared__ float xl[DIN + 2];
    for (int k = j; k < DIN; k += 128) xl[k] = x_sub[(size_t)i * DIN + k];
    if (j == 0) {
        float n0 = 0.f, n1 = 0.f;
        if (i < E_CNT)            { n0 = names[src[i]];          n1 = names[dst[i]]; }
        else if (i < 2 * E_CNT)   { n0 = names[dst[i - E_CNT]];  n1 = names[src[i - E_CNT]]; }
        xl[DIN] = n0; xl[DIN + 1] = n1;
    }
    __syncthreads();
    float acc = b_tune[j];
    #pragma unroll 2
    for (int k = 0; k < DIN + 2; ++k) acc += xl[k] * W_tune[k * HDIM + j];
    zt[(size_t)i * HDIM + j] = acc;
}

// ---------------------------------------------------------------------------
// Per-row pre kernel. Writes VU = [V | U] (1024 x 256) and dlt.
// ---------------------------------------------------------------------------
__global__ __launch_bounds__(128)
void ew_pre(const float* __restrict__ zt, const float* __restrict__ uc_prev,
            const float* __restrict__ rms_scale, const float* __restrict__ W_B,
            const float* __restrict__ b_B, const float* __restrict__ W_dt,
            const float* __restrict__ b_dt, const float* __restrict__ A_log,
            const float* __restrict__ m_vec, const int* __restrict__ act_ids,
            float* __restrict__ VU, float* __restrict__ dlt)
{
    const int i = blockIdx.x, j = threadIdx.x;
    __shared__ float xs[HDIM];
    __shared__ float red[HDIM];

    float x = zt[(size_t)i * HDIM + j];
    if (uc_prev) {
        float g = uc_prev[(size_t)i * HDIM + j];
        float g3 = g * g * g;
        x += 0.5f * g * (1.0f + tanhf(0.7978845608028654f * (g + 0.044715f * g3)));
    }
    red[j] = x * x;
    __syncthreads();
    #pragma unroll
    for (int s = 64; s > 0; s >>= 1) { if (j < s) red[j] += red[j + s]; __syncthreads(); }
    const float rms = sqrtf(red[0]) * 0.08838834764831845f;  // /sqrt(128)
    const float xn = rms_scale[j] * x / (rms + 1e-8f);
    xs[j] = xn;
    __syncthreads();
    red[j] = xn * W_dt[j];
    __syncthreads();
    #pragma unroll
    for (int s = 64; s > 0; s >>= 1) { if (j < s) red[j] += red[j + s]; __syncthreads(); }
    const float dd = red[0] + b_dt[0];
    const float delta = dd > 0.f ? dd + log1pf(expf(-dd)) : log1pf(expf(dd));

    float acc = b_B[j];
    #pragma unroll 8
    for (int k = 0; k < HDIM; ++k) acc += xs[k] * W_B[k * HDIM + j];

    VU[(size_t)i * 256 + j] = acc * delta;                               // V
    const int aid = act_ids[i];
    VU[(size_t)i * 256 + 128 + j] =
        m_vec[(size_t)aid * HDIM + j] * expf(-delta * expf(A_log[j]));   // U
    if (j == 0) dlt[i] = delta;
}

// ---------------------------------------------------------------------------
// Split-K fp32 GEMM. K=1024 total, blockIdx.z selects K-chunk of `klen`.
// A rows stacked: rb<16 -> A0, else A1 (A row stride = 1024 floats).
// Writes partial C chunk s at Cp + s*sstride. Tile 64x64, BK=32, 256 thr,
// 4x4 microtile, register prefetch of next k-step.
// Blocks with (rb >= rb_split && cb >= cb_limit) exit immediately.
// ---------------------------------------------------------------------------
#define GBK 32
__global__ __launch_bounds__(256)
void gemm_sk(const float* __restrict__ A0, const float* __restrict__ A1,
             const float* __restrict__ B, int ldb,
             float* __restrict__ Cp, int ldc, size_t sstride,
             int klen, int rb_split, int cb_limit)
{
    const int cb = blockIdx.x, rb = blockIdx.y, sz = blockIdx.z;
    if (rb >= rb_split && cb >= cb_limit) return;

    __shared__ float As[GBK][68];   // transposed [k][r], padded
    __shared__ float Bs[GBK][64];

    const int tid = threadIdx.x;
    const float* A = (rb < 16) ? (A0 + (size_t)rb * 64 * 1024)
                               : (A1 + (size_t)(rb - 16) * 64 * 1024);
    const int col0 = cb * 64;
    const int kbase = sz * klen;

    const int ar = tid >> 2;            // 0..63
    const int ac = (tid & 3) << 2;      // 0,4,8,12
    const int bk = tid >> 3;            // 0..31
    const int bc = (tid & 7) << 2;      // 0..28
    const int ty = tid >> 4, tx = tid & 15;

    float acc[4][4] = {};

    const float* arow = A + (size_t)ar * 1024 + kbase + ac;
    const float* brow = B + (size_t)(kbase + bk) * ldb + col0 + bc;

    float4 a0 = *(const float4*)(arow);
    float4 a1 = *(const float4*)(arow + 16);
    float4 b0 = *(const float4*)(brow);
    float4 b1 = *(const float4*)(brow + 32);

    for (int k0 = 0; k0 < klen; k0 += GBK) {
        __syncthreads();
        As[ac + 0][ar] = a0.x; As[ac + 1][ar] = a0.y;
        As[ac + 2][ar] = a0.z; As[ac + 3][ar] = a0.w;
        As[ac + 16][ar] = a1.x; As[ac + 17][ar] = a1.y;
        As[ac + 18][ar] = a1.z; As[ac + 19][ar] = a1.w;
        *(float4*)&Bs[bk][bc] = b0;
        *(float4*)&Bs[bk][bc + 32] = b1;
        __syncthreads();
        if (k0 + GBK < klen) {          // prefetch next k-step under the FMAs
            a0 = *(const float4*)(arow + k0 + GBK);
            a1 = *(const float4*)(arow + k0 + GBK + 16);
            b0 = *(const float4*)(brow + (size_t)(k0 + GBK) * ldb);
            b1 = *(const float4*)(brow + (size_t)(k0 + GBK) * ldb + 32);
        }
        #pragma unroll
        for (int kk = 0; kk < GBK; ++kk) {
            float4 av = *(const float4*)&As[kk][ty * 4];
            float4 bv = *(const float4*)&Bs[kk][tx * 4];
            acc[0][0] += av.x * bv.x; acc[0][1] += av.x * bv.y;
            acc[0][2] += av.x * bv.z; acc[0][3] += av.x * bv.w;
            acc[1][0] += av.y * bv.x; acc[1][1] += av.y * bv.y;
            acc[1][2] += av.y * bv.z; acc[1][3] += av.y * bv.w;
            acc[2][0] += av.z * bv.x; acc[2][1] += av.z * bv.y;
            acc[2][2] += av.z * bv.z; acc[2][3] += av.z * bv.w;
            acc[3][0] += av.w * bv.x; acc[3][1] += av.w * bv.y;
            acc[3][2] += av.w * bv.z; acc[3][3] += av.w * bv.w;
        }
    }

    float* crow = Cp + sstride * sz + (size_t)(rb * 64 + ty * 4) * ldc + col0 + tx * 4;
    #pragma unroll
    for (int ii = 0; ii < 4; ++ii) {
        float4 v; v.x = acc[ii][0]; v.y = acc[ii][1]; v.z = acc[ii][2]; v.w = acc[ii][3];
        *(float4*)(crow + (size_t)ii * ldc) = v;
    }
}

// ---------------------------------------------------------------------------
// red1: reduce R1 partials (S=4, 2048x256) -> BIGB [1024x512] = [W|Y1'|P|Q]
//       and G = V - 0.1*W
// ---------------------------------------------------------------------------
__global__ __launch_bounds__(256)
void red1(const float* __restrict__ Cp, const float* __restrict__ VU,
          float* __restrict__ BIGB, float* __restrict__ G)
{
    const int idx = blockIdx.x * 256 + threadIdx.x;    // 524288
    float v = Cp[idx] + Cp[524288 + idx] + Cp[1048576 + idx] + Cp[1572864 + idx];
    const int r = idx >> 8, c = idx & 255;
    const int m = r & 1023, half = r >> 10, src = c >> 7, j = c & 127;
    const int dc = (half ? 128 : 0) + (src ? 256 : 0);
    BIGB[(size_t)m * 512 + dc + j] = v;
    if (!(half | src)) G[(size_t)m * 128 + j] = VU[(size_t)m * 256 + j] - 0.1f * v;
}

// ---------------------------------------------------------------------------
// red2: reduce R2 partials (S=2, 2048x512).
//  rows 0-1023  -> R2OUT [1024x512] = [dLW | Y3p | R2 | R3]; dLW also -> R3B[:,128:256]
//  rows 1024-2047 cols 0:128 -> LW -> R3B[:,0:128]
// ---------------------------------------------------------------------------
__global__ __launch_bounds__(256)
void red2(const float* __restrict__ Cp, float* __restrict__ R2OUT,
          float* __restrict__ R3B)
{
    const int idx = blockIdx.x * 256 + threadIdx.x;    // 655360 total
    if (idx < 524288) {
        const int i = idx >> 9, c = idx & 511;
        const float v = Cp[idx] + Cp[1048576 + idx];
        R2OUT[idx] = v;
        if (c < 128) R3B[(size_t)i * 256 + 128 + c] = v;   // dLW copy
    } else {
        const int t = idx - 524288;                    // 0..131071
        const int i = t >> 7, j = t & 127;
        const size_t off = (size_t)(1024 + i) * 512 + j;
        const float v = Cp[off] + Cp[1048576 + off];
        R3B[(size_t)i * 256 + j] = v;                  // LW
    }
}

// ---------------------------------------------------------------------------
// ew_post (fused reduce of R3 partials, S=8, 1024x256):
// out = U - 0.1 Q + 0.01 R2 + 0.005 R3
//     + sum_k w_k (G + t(-0.1 Y1 + 0.01 Y2) + 0.005 t^2 Y3) e^{dA t}
// Y1 = Y1' - 0.1 dLW;  Y2 = dLW - 0.1*(dL@LW);  Y3 = Y3p - 0.1*(dL@dLW)
// ---------------------------------------------------------------------------
__global__ __launch_bounds__(256)
void ew_post(const float* __restrict__ P3, const float* __restrict__ BIGB,
             const float* __restrict__ R2OUT, const float* __restrict__ G,
             const float* __restrict__ VU, const float* __restrict__ dlt,
             const float* __restrict__ A_log, float* __restrict__ out)
{
    const int idx = blockIdx.x * 256 + threadIdx.x;    // 131072
    const int i = idx >> 7, j = idx & 127;

    float y2i = 0.f, y3i = 0.f;
    #pragma unroll
    for (int s = 0; s < 8; ++s) {
        y2i += P3[(size_t)s * 262144 + (size_t)i * 256 + j];
        y3i += P3[(size_t)s * 262144 + (size_t)i * 256 + 128 + j];
    }
    const size_t rb2 = (size_t)i * 512;
    const float dLW = R2OUT[rb2 + j];
    const float y3p = R2OUT[rb2 + 128 + j];
    const float r2  = R2OUT[rb2 + 256 + j];
    const float r3  = R2OUT[rb2 + 384 + j];
    const float y1  = BIGB[rb2 + 128 + j] - 0.1f * dLW;
    const float q   = BIGB[rb2 + 384 + j];
    const float y2  = dLW - 0.1f * y2i;
    const float y3  = y3p - 0.1f * y3i;
    const float g   = G[idx];
    const float dA  = -dlt[i] * expf(A_log[j]);
    const float bl  = -0.1f * y1 + 0.01f * y2;
    const float cq  = 0.005f * y3;
    float integ = 0.f;
    #pragma unroll
    for (int k = 0; k < 8; ++k) {
        const float t = c_t[k];
        integ += c_w[k] * (g + t * bl + t * t * cq) * expf(dA * t);
    }
    out[idx] = VU[(size_t)i * 256 + 128 + j] - 0.1f * q + 0.01f * r2 + 0.005f * r3 + integ;
}

// ---------------------------------------------------------------------------
extern "C" void kernel_launch(void* const* d_in, const int* in_sizes, int n_in,
                              void* d_out, int out_size, void* d_ws, size_t ws_size,
                              hipStream_t stream)
{
    const float* L      = (const float*)d_in[0];
    const float* dL     = (const float*)d_in[1];
    const float* x_sub  = (const float*)d_in[2];
    const float* m1     = (const float*)d_in[3];
    const float* m2     = (const float*)d_in[4];
    const float* names  = (const float*)d_in[5];
    const float* rms1   = (const float*)d_in[6];
    const float* rms2   = (const float*)d_in[7];
    const float* W_tune = (const float*)d_in[8];
    const float* b_tune = (const float*)d_in[9];
    const float* W_B1   = (const float*)d_in[10];
    const float* b_B1   = (const float*)d_in[11];
    const float* W_B2   = (const float*)d_in[12];
    const float* b_B2   = (const float*)d_in[13];
    const float* W_dt   = (const float*)d_in[14];
    const float* b_dt   = (const float*)d_in[15];
    const float* A1     = (const float*)d_in[16];
    const float* A2     = (const float*)d_in[17];
    const int*   src    = (const int*)d_in[18];
    const int*   dst    = (const int*)d_in[19];
    const int*   act    = (const int*)d_in[20];
    float* out = (float*)d_out;

    // Workspace layout (floats), ~15.7 MB total
    float* ws    = (float*)d_ws;
    float* zt    = ws;                   // 131072
    float* VU    = zt  + 131072;         // 262144  [V|U]
    float* G     = VU  + 262144;         // 131072
    float* BIGB  = G   + 131072;         // 524288  [W|Y1'|P|Q]
    float* R2OUT = BIGB + 524288;        // 524288  [dLW|Y3p|R2|R3]
    float* R3B   = R2OUT + 524288;       // 262144  [LW|dLW]
    float* dlt   = R3B + 262144;         // 1024
    float* Part  = dlt + 1024;           // 2097152 shared split-K partials

    ew_zt<<<dim3(1024), dim3(128), 0, stream>>>(x_sub, names, src, dst, W_tune, b_tune, zt);

    for (int s = 0; s < 2; ++s) {
        ew_pre<<<dim3(1024), dim3(128), 0, stream>>>(
            zt, s ? out : nullptr,
            s ? rms2 : rms1, s ? W_B2 : W_B1, s ? b_B2 : b_B1,
            W_dt, b_dt, s ? A2 : A1, s ? m2 : m1, act, VU, dlt);

        // R1: [L;dL] @ [V|U]  (M=2048, N=256), split S=4 (klen=256)
        gemm_sk<<<dim3(4, 32, 4), dim3(256), 0, stream>>>(
            L, dL, VU, 256, Part, 256, (size_t)524288, 256, 32, 4);
        red1<<<dim3(2048), dim3(256), 0, stream>>>(Part, VU, BIGB, G);

        // R2: [dL; L] @ [W|Y1'|P|Q]  (M=2048, N=512), split S=2 (klen=512);
        // L-half restricted to cols 0:128 (cb<2)
        gemm_sk<<<dim3(8, 32, 2), dim3(256), 0, stream>>>(
            dL, L, BIGB, 512, Part, 512, (size_t)1048576, 512, 16, 2);
        red2<<<dim3(2560), dim3(256), 0, stream>>>(Part, R2OUT, R3B);

        // R3: dL @ [LW | dLW]  (M=1024, N=256), split S=8 (klen=128)
        gemm_sk<<<dim3(4, 16, 8), dim3(256), 0, stream>>>(
            dL, dL, R3B, 256, Part, 256, (size_t)262144, 128, 32, 4);

        ew_post<<<dim3(512), dim3(256), 0, stream>>>(
            Part, BIGB, R2OUT, G, VU, dlt, s ? A2 : A1, out + (size_t)s * 131072);
    }
}

// Round 3
// 129.963 us; speedup vs baseline: 3.1487x; 1.4733x over previous
//
#include <hip/hip_runtime.h>
#include <math.h>

// Problem constants
#define N_A   1024
#define HDIM  128
#define DIN   172
#define E_CNT 256

typedef __attribute__((ext_vector_type(8))) short bf16x8;
typedef __attribute__((ext_vector_type(4))) float f32x4;

__device__ __forceinline__ unsigned short f2bf(float x) {
    unsigned int u = __float_as_uint(x);
    unsigned int r = (u + 0x7fffu + ((u >> 16) & 1u)) >> 16;
    return (unsigned short)r;
}

// Gauss-Legendre nodes/weights mapped to [0,1] (tau=1)
__constant__ float c_t[8] = {
    0.4082826787521751f, 0.2372337950418355f, 0.10166676129318665f, 0.019855071751231843f,
    0.5917173212478249f, 0.7627662049581645f, 0.8983332387068134f, 0.9801449282487682f};
__constant__ float c_w[8] = {
    0.181341891689181f, 0.15685332293894365f, 0.11119051722668725f, 0.05061426814518815f,
    0.181341891689181f, 0.15685332293894365f, 0.11119051722668725f, 0.05061426814518815f};

// ---------------------------------------------------------------------------
// fp32 -> bf16 convert for L and dL (A operands, row-major K-contiguous)
// ---------------------------------------------------------------------------
__global__ __launch_bounds__(256)
void conv_bf16(const float* __restrict__ L, const float* __restrict__ dL,
               unsigned short* __restrict__ Lb, unsigned short* __restrict__ dLb)
{
    const int t = blockIdx.x * 256 + threadIdx.x;      // 524288 threads, 4 elems each
    const float* src = (t < 262144) ? L : dL;
    unsigned short* dst = (t < 262144) ? Lb : dLb;
    const int q = (t < 262144) ? t : t - 262144;
    float4 v = *(const float4*)(src + (size_t)q * 4);
    ushort4 o;
    o.x = f2bf(v.x); o.y = f2bf(v.y); o.z = f2bf(v.z); o.w = f2bf(v.w);
    *(ushort4*)(dst + (size_t)q * 4) = o;
}

// ---------------------------------------------------------------------------
// zt = [x_sub | neigh] @ W_tune + b_tune      (per-row kernel, K=174)
// ---------------------------------------------------------------------------
__global__ __launch_bounds__(128)
void ew_zt(const float* __restrict__ x_sub, const float* __restrict__ names,
           const int* __restrict__ src, const int* __restrict__ dst,
           const float* __restrict__ W_tune, const float* __restrict__ b_tune,
           float* __restrict__ zt)
{
    const int i = blockIdx.x, j = threadIdx.x;
    __shared__ float xl[DIN + 2];
    for (int k = j; k < DIN; k += 128) xl[k] = x_sub[(size_t)i * DIN + k];
    if (j == 0) {
        float n0 = 0.f, n1 = 0.f;
        if (i < E_CNT)            { n0 = names[src[i]];          n1 = names[dst[i]]; }
        else if (i < 2 * E_CNT)   { n0 = names[dst[i - E_CNT]];  n1 = names[src[i - E_CNT]]; }
        xl[DIN] = n0; xl[DIN + 1] = n1;
    }
    __syncthreads();
    float acc = b_tune[j];
    #pragma unroll 2
    for (int k = 0; k < DIN + 2; ++k) acc += xl[k] * W_tune[k * HDIM + j];
    zt[(size_t)i * HDIM + j] = acc;
}

// ---------------------------------------------------------------------------
// Per-row pre kernel. Writes VU fp32 [i][256] = [V|U], transposed bf16
// VUt [256][1024], and dlt.
// ---------------------------------------------------------------------------
__global__ __launch_bounds__(128)
void ew_pre(const float* __restrict__ zt, const float* __restrict__ uc_prev,
            const float* __restrict__ rms_scale, const float* __restrict__ W_B,
            const float* __restrict__ b_B, const float* __restrict__ W_dt,
            const float* __restrict__ b_dt, const float* __restrict__ A_log,
            const float* __restrict__ m_vec, const int* __restrict__ act_ids,
            float* __restrict__ VU, unsigned short* __restrict__ VUt,
            float* __restrict__ dlt)
{
    const int i = blockIdx.x, j = threadIdx.x;
    __shared__ float xs[HDIM];
    __shared__ float red[HDIM];

    float x = zt[(size_t)i * HDIM + j];
    if (uc_prev) {
        float g = uc_prev[(size_t)i * HDIM + j];
        float g3 = g * g * g;
        x += 0.5f * g * (1.0f + tanhf(0.7978845608028654f * (g + 0.044715f * g3)));
    }
    red[j] = x * x;
    __syncthreads();
    #pragma unroll
    for (int s = 64; s > 0; s >>= 1) { if (j < s) red[j] += red[j + s]; __syncthreads(); }
    const float rms = sqrtf(red[0]) * 0.08838834764831845f;  // /sqrt(128)
    const float xn = rms_scale[j] * x / (rms + 1e-8f);
    xs[j] = xn;
    __syncthreads();
    red[j] = xn * W_dt[j];
    __syncthreads();
    #pragma unroll
    for (int s = 64; s > 0; s >>= 1) { if (j < s) red[j] += red[j + s]; __syncthreads(); }
    const float dd = red[0] + b_dt[0];
    const float delta = dd > 0.f ? dd + log1pf(expf(-dd)) : log1pf(expf(dd));

    float acc = b_B[j];
    #pragma unroll 8
    for (int k = 0; k < HDIM; ++k) acc += xs[k] * W_B[k * HDIM + j];

    const float V = acc * delta;
    const int aid = act_ids[i];
    const float U = m_vec[(size_t)aid * HDIM + j] * expf(-delta * expf(A_log[j]));

    VU[(size_t)i * 256 + j] = V;
    VU[(size_t)i * 256 + 128 + j] = U;
    VUt[(size_t)j * 1024 + i] = f2bf(V);
    VUt[(size_t)(128 + j) * 1024 + i] = f2bf(U);
    if (j == 0) dlt[i] = delta;
}

// ---------------------------------------------------------------------------
// MFMA bf16 GEMM, split-K. A row stride = 1024 bf16, rows stacked:
// rb<16 -> A0, else A1. Bt is B TRANSPOSED [n][1024] bf16.
// Tile 64x64, 4 waves (2x2), each wave 32x32 via 2x2 mfma_16x16x32 frags.
// Writes fp32 partials at Cp + sstride*sz. Blocks rb>=16 && cb>=cb_limit exit.
// ---------------------------------------------------------------------------
#define LDP 40   // LDS pitch (bf16 elems) to break bank conflicts
__global__ __launch_bounds__(256)
void gemm_mfma(const unsigned short* __restrict__ A0, const unsigned short* __restrict__ A1,
               const unsigned short* __restrict__ Bt,
               float* __restrict__ Cp, int ldc, size_t sstride,
               int klen, int cb_limit)
{
    const int cb = blockIdx.x, rb = blockIdx.y, sz = blockIdx.z;
    if (rb >= 16 && cb >= cb_limit) return;

    __shared__ unsigned short As[64 * LDP];
    __shared__ unsigned short Bs[64 * LDP];

    const int tid = threadIdx.x;
    const unsigned short* A = (rb < 16) ? (A0 + (size_t)rb * 64 * 1024)
                                        : (A1 + (size_t)(rb - 16) * 64 * 1024);
    const unsigned short* Bp = Bt + (size_t)cb * 64 * 1024;
    const int kbase = sz * klen;

    const int srow = tid >> 2;            // 0..63
    const int skp  = (tid & 3) << 3;      // 0,8,16,24

    const unsigned short* ag = A  + (size_t)srow * 1024 + kbase + skp;
    const unsigned short* bg = Bp + (size_t)srow * 1024 + kbase + skp;

    const int lane = tid & 63;
    const int w = tid >> 6;
    const int wrow = (w >> 1) * 32, wcol = (w & 1) * 32;
    const int fr = lane & 15;             // frag row/col
    const int fk = (lane >> 4) << 3;      // frag k offset

    f32x4 acc[2][2] = {};

    bf16x8 av = *(const bf16x8*)ag;
    bf16x8 bv = *(const bf16x8*)bg;

    for (int k0 = 0; k0 < klen; k0 += 32) {
        __syncthreads();
        *(bf16x8*)&As[srow * LDP + skp] = av;
        *(bf16x8*)&Bs[srow * LDP + skp] = bv;
        __syncthreads();
        if (k0 + 32 < klen) {             // prefetch next k-step under MFMAs
            av = *(const bf16x8*)(ag + k0 + 32);
            bv = *(const bf16x8*)(bg + k0 + 32);
        }
        bf16x8 a0 = *(const bf16x8*)&As[(wrow + fr) * LDP + fk];
        bf16x8 a1 = *(const bf16x8*)&As[(wrow + 16 + fr) * LDP + fk];
        bf16x8 b0 = *(const bf16x8*)&Bs[(wcol + fr) * LDP + fk];
        bf16x8 b1 = *(const bf16x8*)&Bs[(wcol + 16 + fr) * LDP + fk];
        acc[0][0] = __builtin_amdgcn_mfma_f32_16x16x32_bf16(a0, b0, acc[0][0], 0, 0, 0);
        acc[0][1] = __builtin_amdgcn_mfma_f32_16x16x32_bf16(a0, b1, acc[0][1], 0, 0, 0);
        acc[1][0] = __builtin_amdgcn_mfma_f32_16x16x32_bf16(a1, b0, acc[1][0], 0, 0, 0);
        acc[1][1] = __builtin_amdgcn_mfma_f32_16x16x32_bf16(a1, b1, acc[1][1], 0, 0, 0);
    }

    // C/D layout: col = lane&15, row = (lane>>4)*4 + r  (per 16x16 frag)
    float* Cbase = Cp + sstride * sz
                 + (size_t)(rb * 64 + wrow + ((lane >> 4) << 2)) * ldc
                 + cb * 64 + wcol + fr;
    #pragma unroll
    for (int m = 0; m < 2; ++m)
        #pragma unroll
        for (int n = 0; n < 2; ++n)
            #pragma unroll
            for (int r = 0; r < 4; ++r)
                Cbase[(size_t)(m * 16 + r) * ldc + n * 16] = acc[m][n][r];
}

// ---------------------------------------------------------------------------
// red1: reduce R1 partials (S=2, 2048x256) ->
//   BIGBt bf16 [512][1024] = rows [W|Y1'|P|Q] transposed (R2 GEMM input)
//   YQ fp32 [1024][256] = [Y1' | Q]   (ew_post input)
//   G fp32 = V - 0.1*W
// ---------------------------------------------------------------------------
__global__ __launch_bounds__(256)
void red1(const float* __restrict__ Cp, const float* __restrict__ VU,
          unsigned short* __restrict__ BIGBt, float* __restrict__ YQ,
          float* __restrict__ G)
{
    const int idx = blockIdx.x * 256 + threadIdx.x;    // 524288
    const float v = Cp[idx] + Cp[524288 + idx];
    const int r = idx >> 8, c = idx & 255;
    const int m = r & 1023, half = r >> 10, srcc = c >> 7, j = c & 127;
    const int dc = half * 128 + srcc * 256;
    BIGBt[(size_t)(dc + j) * 1024 + m] = f2bf(v);
    if (half == 1) YQ[(size_t)m * 256 + srcc * 128 + j] = v;   // Y1' (srcc=0) / Q (srcc=1)
    else if (srcc == 0) G[(size_t)m * 128 + j] = VU[(size_t)m * 256 + j] - 0.1f * v;
}

// ---------------------------------------------------------------------------
// red2: reduce R2 partials (S=2, 2048x512).
//  rows 0-1023  -> R2OUT fp32 [1024x512] = [dLW|Y3p|R2|R3]; dLW -> R3Bt rows 128:256
//  rows 1024-2047 cols 0:128 (LW) -> R3Bt rows 0:128
// ---------------------------------------------------------------------------
__global__ __launch_bounds__(256)
void red2(const float* __restrict__ Cp, float* __restrict__ R2OUT,
          unsigned short* __restrict__ R3Bt)
{
    const int idx = blockIdx.x * 256 + threadIdx.x;    // 655360 total
    if (idx < 524288) {
        const int i = idx >> 9, c = idx & 511;
        const float v = Cp[idx] + Cp[1048576 + idx];
        R2OUT[idx] = v;
        if (c < 128) R3Bt[(size_t)(128 + c) * 1024 + i] = f2bf(v);   // dLW
    } else {
        const int t = idx - 524288;                    // 0..131071
        const int i = t >> 7, j = t & 127;
        const size_t off = (size_t)(1024 + i) * 512 + j;
        const float v = Cp[off] + Cp[1048576 + off];
        R3Bt[(size_t)j * 1024 + i] = f2bf(v);                        // LW
    }
}

// ---------------------------------------------------------------------------
// ew_post (fused reduce of R3 partials, S=4, 1024x256):
// out = U - 0.1 Q + 0.01 R2 + 0.005 R3
//     + sum_k w_k (G + t(-0.1 Y1 + 0.01 Y2) + 0.005 t^2 Y3) e^{dA t}
// Y1 = Y1' - 0.1 dLW;  Y2 = dLW - 0.1*(dL@LW);  Y3 = Y3p - 0.1*(dL@dLW)
// ---------------------------------------------------------------------------
__global__ __launch_bounds__(256)
void ew_post(const float* __restrict__ P3, const float* __restrict__ YQ,
             const float* __restrict__ R2OUT, const float* __restrict__ G,
             const float* __restrict__ VU, const float* __restrict__ dlt,
             const float* __restrict__ A_log, float* __restrict__ out)
{
    const int idx = blockIdx.x * 256 + threadIdx.x;    // 131072
    const int i = idx >> 7, j = idx & 127;

    float y2i = 0.f, y3i = 0.f;
    #pragma unroll
    for (int s = 0; s < 4; ++s) {
        y2i += P3[(size_t)s * 262144 + (size_t)i * 256 + j];
        y3i += P3[(size_t)s * 262144 + (size_t)i * 256 + 128 + j];
    }
    const size_t rb2 = (size_t)i * 512;
    const float dLW = R2OUT[rb2 + j];
    const float y3p = R2OUT[rb2 + 128 + j];
    const float r2  = R2OUT[rb2 + 256 + j];
    const float r3  = R2OUT[rb2 + 384 + j];
    const float y1  = YQ[(size_t)i * 256 + j] - 0.1f * dLW;
    const float q   = YQ[(size_t)i * 256 + 128 + j];
    const float y2  = dLW - 0.1f * y2i;
    const float y3  = y3p - 0.1f * y3i;
    const float g   = G[idx];
    const float dA  = -dlt[i] * expf(A_log[j]);
    const float bl  = -0.1f * y1 + 0.01f * y2;
    const float cq  = 0.005f * y3;
    float integ = 0.f;
    #pragma unroll
    for (int k = 0; k < 8; ++k) {
        const float t = c_t[k];
        integ += c_w[k] * (g + t * bl + t * t * cq) * expf(dA * t);
    }
    out[idx] = VU[(size_t)i * 256 + 128 + j] - 0.1f * q + 0.01f * r2 + 0.005f * r3 + integ;
}

// ---------------------------------------------------------------------------
extern "C" void kernel_launch(void* const* d_in, const int* in_sizes, int n_in,
                              void* d_out, int out_size, void* d_ws, size_t ws_size,
                              hipStream_t stream)
{
    const float* L      = (const float*)d_in[0];
    const float* dL     = (const float*)d_in[1];
    const float* x_sub  = (const float*)d_in[2];
    const float* m1     = (const float*)d_in[3];
    const float* m2     = (const float*)d_in[4];
    const float* names  = (const float*)d_in[5];
    const float* rms1   = (const float*)d_in[6];
    const float* rms2   = (const float*)d_in[7];
    const float* W_tune = (const float*)d_in[8];
    const float* b_tune = (const float*)d_in[9];
    const float* W_B1   = (const float*)d_in[10];
    const float* b_B1   = (const float*)d_in[11];
    const float* W_B2   = (const float*)d_in[12];
    const float* b_B2   = (const float*)d_in[13];
    const float* W_dt   = (const float*)d_in[14];
    const float* b_dt   = (const float*)d_in[15];
    const float* A1     = (const float*)d_in[16];
    const float* A2     = (const float*)d_in[17];
    const int*   src    = (const int*)d_in[18];
    const int*   dst    = (const int*)d_in[19];
    const int*   act    = (const int*)d_in[20];
    float* out = (float*)d_out;

    // Workspace layout (~20 MB)
    float* ws    = (float*)d_ws;
    float* zt    = ws;                    // 131072
    float* VU    = zt  + 131072;          // 262144  fp32 [V|U]
    float* G     = VU  + 262144;          // 131072
    float* YQ    = G   + 131072;          // 262144  fp32 [Y1'|Q]
    float* R2OUT = YQ  + 262144;          // 524288  fp32 [dLW|Y3p|R2|R3]
    float* dlt   = R2OUT + 524288;        // 1024
    float* Part  = dlt + 1024;            // 2097152 split-K partials
    unsigned short* Lb    = (unsigned short*)(Part + 2097152);  // 1048576
    unsigned short* dLb   = Lb   + 1048576;                     // 1048576
    unsigned short* VUt   = dLb  + 1048576;                     // 262144 [V|U]^T
    unsigned short* BIGBt = VUt  + 262144;                      // 524288 [W|Y1'|P|Q]^T
    unsigned short* R3Bt  = BIGBt + 524288;                     // 262144 [LW|dLW]^T

    conv_bf16<<<dim3(2048), dim3(256), 0, stream>>>(L, dL, Lb, dLb);
    ew_zt<<<dim3(1024), dim3(128), 0, stream>>>(x_sub, names, src, dst, W_tune, b_tune, zt);

    for (int s = 0; s < 2; ++s) {
        ew_pre<<<dim3(1024), dim3(128), 0, stream>>>(
            zt, s ? out : nullptr,
            s ? rms2 : rms1, s ? W_B2 : W_B1, s ? b_B2 : b_B1,
            W_dt, b_dt, s ? A2 : A1, s ? m2 : m1, act, VU, VUt, dlt);

        // R1: [L;dL] @ [V|U]  (M=2048, N=256, K=1024), split S=2
        gemm_mfma<<<dim3(4, 32, 2), dim3(256), 0, stream>>>(
            Lb, dLb, VUt, Part, 256, (size_t)524288, 512, 8);
        red1<<<dim3(2048), dim3(256), 0, stream>>>(Part, VU, BIGBt, YQ, G);

        // R2: [dL; L] @ [W|Y1'|P|Q]  (M=2048, N=512), split S=2;
        // L-half restricted to cols 0:128 (cb<2)
        gemm_mfma<<<dim3(8, 32, 2), dim3(256), 0, stream>>>(
            dLb, Lb, BIGBt, Part, 512, (size_t)1048576, 512, 2);
        red2<<<dim3(2560), dim3(256), 0, stream>>>(Part, R2OUT, R3Bt);

        // R3: dL @ [LW | dLW]  (M=1024, N=256), split S=4
        gemm_mfma<<<dim3(4, 16, 4), dim3(256), 0, stream>>>(
            dLb, dLb, R3Bt, Part, 256, (size_t)262144, 256, 8);

        ew_post<<<dim3(512), dim3(256), 0, stream>>>(
            Part, YQ, R2OUT, G, VU, dlt, s ? A2 : A1, out + (size_t)s * 131072);
    }
}

// Round 4
// 121.127 us; speedup vs baseline: 3.3784x; 1.0730x over previous
//
#include <hip/hip_runtime.h>
#include <math.h>

#define N_A   1024
#define HDIM  128
#define DIN   172
#define E_CNT 256
#define LP    72      // LDS pitch in bf16 elems

typedef __attribute__((ext_vector_type(8))) short bf16x8;
typedef __attribute__((ext_vector_type(4))) float f32x4;

__device__ __forceinline__ unsigned short f2bf(float x) {
    unsigned int u = __float_as_uint(x);
    unsigned int r = (u + 0x7fffu + ((u >> 16) & 1u)) >> 16;
    return (unsigned short)r;
}

// Gauss-Legendre nodes/weights mapped to [0,1] (tau=1)
__constant__ float c_t[8] = {
    0.4082826787521751f, 0.2372337950418355f, 0.10166676129318665f, 0.019855071751231843f,
    0.5917173212478249f, 0.7627662049581645f, 0.8983332387068134f, 0.9801449282487682f};
__constant__ float c_w[8] = {
    0.181341891689181f, 0.15685332293894365f, 0.11119051722668725f, 0.05061426814518815f,
    0.181341891689181f, 0.15685332293894365f, 0.11119051722668725f, 0.05061426814518815f};

// ---------------------------------------------------------------------------
// fp32 -> bf16 for L and dL (A operands, K-contiguous)
// ---------------------------------------------------------------------------
__global__ __launch_bounds__(256)
void conv_bf16(const float* __restrict__ L, const float* __restrict__ dL,
               unsigned short* __restrict__ Lb, unsigned short* __restrict__ dLb)
{
    const int t = blockIdx.x * 256 + threadIdx.x;      // 524288 threads, 4 elems each
    const float* src = (t < 262144) ? L : dL;
    unsigned short* dst = (t < 262144) ? Lb : dLb;
    const int q = (t < 262144) ? t : t - 262144;
    float4 v = *(const float4*)(src + (size_t)q * 4);
    ushort4 o;
    o.x = f2bf(v.x); o.y = f2bf(v.y); o.z = f2bf(v.z); o.w = f2bf(v.w);
    *(ushort4*)(dst + (size_t)q * 4) = o;
}

// ---------------------------------------------------------------------------
// wave-based 128-wide row reduction (2 waves per block)
// ---------------------------------------------------------------------------
__device__ __forceinline__ float rowsum128(float v, float* red2, int j)
{
    #pragma unroll
    for (int o = 32; o > 0; o >>= 1) v += __shfl_xor(v, o, 64);
    if ((j & 63) == 0) red2[j >> 6] = v;
    __syncthreads();
    const float t = red2[0] + red2[1];
    __syncthreads();
    return t;
}

// ---------------------------------------------------------------------------
// per-row "pre" body: rmsnorm -> delta -> Bz -> V,U ; writes VU/VUt/dlt
// ---------------------------------------------------------------------------
__device__ __forceinline__ void pre_body(
    float x, int i, int j,
    const float* __restrict__ rms_scale, const float* __restrict__ W_B,
    const float* __restrict__ b_B, const float* __restrict__ W_dt,
    const float* __restrict__ b_dt, const float* __restrict__ A_log,
    const float* __restrict__ m_vec, const int* __restrict__ act_ids,
    float* __restrict__ VU, unsigned short* __restrict__ VUt,
    float* __restrict__ dlt, float* xs, float* red2)
{
    const float ss = rowsum128(x * x, red2, j);
    const float rms = sqrtf(ss) * 0.08838834764831845f;   // /sqrt(128)
    const float xn = rms_scale[j] * x / (rms + 1e-8f);
    xs[j] = xn;
    const float dsum = rowsum128(xn * W_dt[j], red2, j);  // includes barrier for xs
    const float dd = dsum + b_dt[0];
    const float delta = dd > 0.f ? dd + log1pf(expf(-dd)) : log1pf(expf(dd));

    float acc = b_B[j];
    #pragma unroll 8
    for (int k = 0; k < HDIM; ++k) acc += xs[k] * W_B[k * HDIM + j];

    const float V = acc * delta;
    const int aid = act_ids[i];
    const float U = m_vec[(size_t)aid * HDIM + j] * expf(-delta * expf(A_log[j]));

    VU[(size_t)i * 256 + j] = V;
    VU[(size_t)i * 256 + 128 + j] = U;
    VUt[(size_t)j * 1024 + i] = f2bf(V);
    VUt[(size_t)(128 + j) * 1024 + i] = f2bf(U);
    if (j == 0) dlt[i] = delta;
}

// ---------------------------------------------------------------------------
// ew_head: zt = [x_sub|neigh]@W_tune + b_tune, then pre(stage 1)
// ---------------------------------------------------------------------------
__global__ __launch_bounds__(128)
void ew_head(const float* __restrict__ x_sub, const float* __restrict__ names,
             const int* __restrict__ src, const int* __restrict__ dst,
             const float* __restrict__ W_tune, const float* __restrict__ b_tune,
             const float* __restrict__ rms1, const float* __restrict__ W_B1,
             const float* __restrict__ b_B1, const float* __restrict__ W_dt,
             const float* __restrict__ b_dt, const float* __restrict__ A1,
             const float* __restrict__ m1, const int* __restrict__ act,
             float* __restrict__ zt, float* __restrict__ VU,
             unsigned short* __restrict__ VUt, float* __restrict__ dlt1)
{
    const int i = blockIdx.x, j = threadIdx.x;
    __shared__ float xl[DIN + 2];
    __shared__ float xs[HDIM];
    __shared__ float red2[2];

    for (int k = j; k < DIN; k += 128) xl[k] = x_sub[(size_t)i * DIN + k];
    if (j == 0) {
        float n0 = 0.f, n1 = 0.f;
        if (i < E_CNT)            { n0 = names[src[i]];          n1 = names[dst[i]]; }
        else if (i < 2 * E_CNT)   { n0 = names[dst[i - E_CNT]];  n1 = names[src[i - E_CNT]]; }
        xl[DIN] = n0; xl[DIN + 1] = n1;
    }
    __syncthreads();
    float acc = b_tune[j];
    #pragma unroll 2
    for (int k = 0; k < DIN + 2; ++k) acc += xl[k] * W_tune[k * HDIM + j];
    zt[(size_t)i * HDIM + j] = acc;

    pre_body(acc, i, j, rms1, W_B1, b_B1, W_dt, b_dt, A1, m1, act,
             VU, VUt, dlt1, xs, red2);
}

// ---------------------------------------------------------------------------
// GA: per slot (blockIdx.x): 0,1 -> type G (LV tile, cols slot*64 of V)
//                            2,3 -> type T (LU and dLU tiles, cols of U)
// epilogue: G = V - 0.1 LV -> GTt rows 0:128 (bf16 ^T) + Gf fp32
//           T = U - 0.1 LU - 0.05 dLU -> GTt rows 128:256
// ---------------------------------------------------------------------------
__global__ __launch_bounds__(256)
void gemm_ga(const unsigned short* __restrict__ Lb, const unsigned short* __restrict__ dLb,
             const unsigned short* __restrict__ VUt, const float* __restrict__ VU,
             unsigned short* __restrict__ GTt, float* __restrict__ Gf)
{
    const int slot = blockIdx.x, rb = blockIdx.y;
    const bool typeT = slot >= 2;
    const int cb = typeT ? slot - 2 : slot;
    const int bn0 = (typeT ? 128 : 0) + cb * 64;

    __shared__ unsigned short AsL[64 * LP];
    __shared__ unsigned short AsD[64 * LP];
    __shared__ unsigned short Bs[64 * LP];

    const int tid = threadIdx.x;
    const int srow = tid >> 2, skc = (tid & 3) << 4;

    const unsigned short* aL = Lb  + (size_t)(rb * 64 + srow) * 1024 + skc;
    const unsigned short* aD = dLb + (size_t)(rb * 64 + srow) * 1024 + skc;
    const unsigned short* bg = VUt + (size_t)(bn0 + srow) * 1024 + skc;

    const int lane = tid & 63, w = tid >> 6;
    const int wrow = (w >> 1) * 32, wcol = (w & 1) * 32;
    const int fr = lane & 15, fg = lane >> 4, fk = fg << 3;

    f32x4 acc[2][2] = {};
    f32x4 acc2[2][2] = {};

    bf16x8 pa0 = *(const bf16x8*)aL, pa1 = *(const bf16x8*)(aL + 8);
    bf16x8 pb0 = *(const bf16x8*)bg, pb1 = *(const bf16x8*)(bg + 8);
    bf16x8 pd0 = {}, pd1 = {};
    if (typeT) { pd0 = *(const bf16x8*)aD; pd1 = *(const bf16x8*)(aD + 8); }

    for (int k0 = 0; k0 < 1024; k0 += 64) {
        __syncthreads();
        *(bf16x8*)&AsL[srow * LP + skc] = pa0; *(bf16x8*)&AsL[srow * LP + skc + 8] = pa1;
        *(bf16x8*)&Bs[srow * LP + skc]  = pb0; *(bf16x8*)&Bs[srow * LP + skc + 8]  = pb1;
        if (typeT) { *(bf16x8*)&AsD[srow * LP + skc] = pd0; *(bf16x8*)&AsD[srow * LP + skc + 8] = pd1; }
        __syncthreads();
        if (k0 + 64 < 1024) {
            pa0 = *(const bf16x8*)(aL + k0 + 64); pa1 = *(const bf16x8*)(aL + k0 + 72);
            pb0 = *(const bf16x8*)(bg + k0 + 64); pb1 = *(const bf16x8*)(bg + k0 + 72);
            if (typeT) { pd0 = *(const bf16x8*)(aD + k0 + 64); pd1 = *(const bf16x8*)(aD + k0 + 72); }
        }
        #pragma unroll
        for (int h = 0; h < 2; ++h) {
            const int ko = h * 32 + fk;
            bf16x8 a0 = *(const bf16x8*)&AsL[(wrow + fr) * LP + ko];
            bf16x8 a1 = *(const bf16x8*)&AsL[(wrow + 16 + fr) * LP + ko];
            bf16x8 b0 = *(const bf16x8*)&Bs[(wcol + fr) * LP + ko];
            bf16x8 b1 = *(const bf16x8*)&Bs[(wcol + 16 + fr) * LP + ko];
            acc[0][0] = __builtin_amdgcn_mfma_f32_16x16x32_bf16(a0, b0, acc[0][0], 0, 0, 0);
            acc[0][1] = __builtin_amdgcn_mfma_f32_16x16x32_bf16(a0, b1, acc[0][1], 0, 0, 0);
            acc[1][0] = __builtin_amdgcn_mfma_f32_16x16x32_bf16(a1, b0, acc[1][0], 0, 0, 0);
            acc[1][1] = __builtin_amdgcn_mfma_f32_16x16x32_bf16(a1, b1, acc[1][1], 0, 0, 0);
            if (typeT) {
                bf16x8 d0 = *(const bf16x8*)&AsD[(wrow + fr) * LP + ko];
                bf16x8 d1 = *(const bf16x8*)&AsD[(wrow + 16 + fr) * LP + ko];
                acc2[0][0] = __builtin_amdgcn_mfma_f32_16x16x32_bf16(d0, b0, acc2[0][0], 0, 0, 0);
                acc2[0][1] = __builtin_amdgcn_mfma_f32_16x16x32_bf16(d0, b1, acc2[0][1], 0, 0, 0);
                acc2[1][0] = __builtin_amdgcn_mfma_f32_16x16x32_bf16(d1, b0, acc2[1][0], 0, 0, 0);
                acc2[1][1] = __builtin_amdgcn_mfma_f32_16x16x32_bf16(d1, b1, acc2[1][1], 0, 0, 0);
            }
        }
    }

    #pragma unroll
    for (int m = 0; m < 2; ++m) {
        const int gm = rb * 64 + wrow + m * 16 + fg * 4;
        #pragma unroll
        for (int n = 0; n < 2; ++n) {
            const int gj = cb * 64 + wcol + n * 16 + fr;   // 0..127
            float gv[4];
            #pragma unroll
            for (int r = 0; r < 4; ++r) {
                if (!typeT)
                    gv[r] = VU[(size_t)(gm + r) * 256 + gj] - 0.1f * acc[m][n][r];
                else
                    gv[r] = VU[(size_t)(gm + r) * 256 + 128 + gj]
                          - 0.1f * acc[m][n][r] - 0.05f * acc2[m][n][r];
            }
            ushort4 tv; tv.x = f2bf(gv[0]); tv.y = f2bf(gv[1]); tv.z = f2bf(gv[2]); tv.w = f2bf(gv[3]);
            *(ushort4*)&GTt[(size_t)((typeT ? 128 : 0) + gj) * 1024 + gm] = tv;
            if (!typeT) {
                #pragma unroll
                for (int r = 0; r < 4; ++r) Gf[(size_t)(gm + r) * 128 + gj] = gv[r];
            }
        }
    }
}

// ---------------------------------------------------------------------------
// single-A 64x64 MFMA core
// ---------------------------------------------------------------------------
__device__ __forceinline__ void core_sa(
    const unsigned short* __restrict__ ag, const unsigned short* __restrict__ bg,
    unsigned short* As, unsigned short* Bs, int klen,
    int srow, int skc, int wrow, int wcol, int fr, int fk, f32x4 (&acc)[2][2])
{
    bf16x8 pa0 = *(const bf16x8*)ag, pa1 = *(const bf16x8*)(ag + 8);
    bf16x8 pb0 = *(const bf16x8*)bg, pb1 = *(const bf16x8*)(bg + 8);
    for (int k0 = 0; k0 < klen; k0 += 64) {
        __syncthreads();
        *(bf16x8*)&As[srow * LP + skc] = pa0; *(bf16x8*)&As[srow * LP + skc + 8] = pa1;
        *(bf16x8*)&Bs[srow * LP + skc] = pb0; *(bf16x8*)&Bs[srow * LP + skc + 8] = pb1;
        __syncthreads();
        if (k0 + 64 < klen) {
            pa0 = *(const bf16x8*)(ag + k0 + 64); pa1 = *(const bf16x8*)(ag + k0 + 72);
            pb0 = *(const bf16x8*)(bg + k0 + 64); pb1 = *(const bf16x8*)(bg + k0 + 72);
        }
        #pragma unroll
        for (int h = 0; h < 2; ++h) {
            const int ko = h * 32 + fk;
            bf16x8 a0 = *(const bf16x8*)&As[(wrow + fr) * LP + ko];
            bf16x8 a1 = *(const bf16x8*)&As[(wrow + 16 + fr) * LP + ko];
            bf16x8 b0 = *(const bf16x8*)&Bs[(wcol + fr) * LP + ko];
            bf16x8 b1 = *(const bf16x8*)&Bs[(wcol + 16 + fr) * LP + ko];
            acc[0][0] = __builtin_amdgcn_mfma_f32_16x16x32_bf16(a0, b0, acc[0][0], 0, 0, 0);
            acc[0][1] = __builtin_amdgcn_mfma_f32_16x16x32_bf16(a0, b1, acc[0][1], 0, 0, 0);
            acc[1][0] = __builtin_amdgcn_mfma_f32_16x16x32_bf16(a1, b0, acc[1][0], 0, 0, 0);
            acc[1][1] = __builtin_amdgcn_mfma_f32_16x16x32_bf16(a1, b1, acc[1][1], 0, 0, 0);
        }
    }
}

// ---------------------------------------------------------------------------
// GB: slots 0,1: H = L@G   -> HY1t rows 0:128 (bf16 ^T)
//     slots 2,3: Y1 = dL@G -> HY1t rows 128:256 + Y1f fp32
//     slots 4,5: S = dL@T  -> Sf fp32
// ---------------------------------------------------------------------------
__global__ __launch_bounds__(256)
void gemm_gb(const unsigned short* __restrict__ Lb, const unsigned short* __restrict__ dLb,
             const unsigned short* __restrict__ GTt,
             unsigned short* __restrict__ HY1t, float* __restrict__ Y1f,
             float* __restrict__ Sf)
{
    const int slot = blockIdx.x, rb = blockIdx.y;
    const unsigned short* A = (slot < 2) ? Lb : dLb;
    const int jbase = ((slot < 2) ? slot : (slot < 4) ? slot - 2 : slot - 4) * 64;
    const int bn0 = (slot < 4) ? jbase : 128 + jbase;

    __shared__ unsigned short As[64 * LP];
    __shared__ unsigned short Bs[64 * LP];

    const int tid = threadIdx.x;
    const int srow = tid >> 2, skc = (tid & 3) << 4;
    const unsigned short* ag = A   + (size_t)(rb * 64 + srow) * 1024 + skc;
    const unsigned short* bg = GTt + (size_t)(bn0 + srow) * 1024 + skc;

    const int lane = tid & 63, w = tid >> 6;
    const int wrow = (w >> 1) * 32, wcol = (w & 1) * 32;
    const int fr = lane & 15, fg = lane >> 4, fk = fg << 3;

    f32x4 acc[2][2] = {};
    core_sa(ag, bg, As, Bs, 1024, srow, skc, wrow, wcol, fr, fk, acc);

    #pragma unroll
    for (int m = 0; m < 2; ++m) {
        const int gm = rb * 64 + wrow + m * 16 + fg * 4;
        #pragma unroll
        for (int n = 0; n < 2; ++n) {
            const int gj = jbase + wcol + n * 16 + fr;
            if (slot < 4) {
                ushort4 tv;
                tv.x = f2bf(acc[m][n][0]); tv.y = f2bf(acc[m][n][1]);
                tv.z = f2bf(acc[m][n][2]); tv.w = f2bf(acc[m][n][3]);
                *(ushort4*)&HY1t[(size_t)((slot < 2 ? 0 : 128) + gj) * 1024 + gm] = tv;
                if (slot >= 2) {
                    #pragma unroll
                    for (int r = 0; r < 4; ++r) Y1f[(size_t)(gm + r) * 128 + gj] = acc[m][n][r];
                }
            } else {
                #pragma unroll
                for (int r = 0; r < 4; ++r) Sf[(size_t)(gm + r) * 128 + gj] = acc[m][n][r];
            }
        }
    }
}

// ---------------------------------------------------------------------------
// GC: dL @ [H|Y1]  (N=256), split-K S=2 -> Part fp32 partials [s][1024][256]
// ---------------------------------------------------------------------------
__global__ __launch_bounds__(256)
void gemm_gc(const unsigned short* __restrict__ dLb, const unsigned short* __restrict__ HY1t,
             float* __restrict__ Part)
{
    const int cb = blockIdx.x, rb = blockIdx.y, sz = blockIdx.z;
    const int kbase = sz * 512;

    __shared__ unsigned short As[64 * LP];
    __shared__ unsigned short Bs[64 * LP];

    const int tid = threadIdx.x;
    const int srow = tid >> 2, skc = (tid & 3) << 4;
    const unsigned short* ag = dLb  + (size_t)(rb * 64 + srow) * 1024 + kbase + skc;
    const unsigned short* bg = HY1t + (size_t)(cb * 64 + srow) * 1024 + kbase + skc;

    const int lane = tid & 63, w = tid >> 6;
    const int wrow = (w >> 1) * 32, wcol = (w & 1) * 32;
    const int fr = lane & 15, fg = lane >> 4, fk = fg << 3;

    f32x4 acc[2][2] = {};
    core_sa(ag, bg, As, Bs, 512, srow, skc, wrow, wcol, fr, fk, acc);

    float* Cb = Part + (size_t)sz * 262144;
    #pragma unroll
    for (int m = 0; m < 2; ++m) {
        const int gm = rb * 64 + wrow + m * 16 + fg * 4;
        #pragma unroll
        for (int n = 0; n < 2; ++n) {
            const int gn = cb * 64 + wcol + n * 16 + fr;
            #pragma unroll
            for (int r = 0; r < 4; ++r) Cb[(size_t)(gm + r) * 256 + gn] = acc[m][n][r];
        }
    }
}

// ---------------------------------------------------------------------------
// post body: out = U - 0.1 S + sum_k w_k (G + t(-0.1 Y1 + 0.01 Y2) + 0.005 t^2 Y3) e^{dA t}
// ---------------------------------------------------------------------------
__device__ __forceinline__ float post_body(
    int i, int j, const float* __restrict__ Part, const float* __restrict__ Gf,
    const float* __restrict__ Y1f, const float* __restrict__ Sf,
    const float* __restrict__ VU, const float* __restrict__ dlt,
    const float* __restrict__ A_log)
{
    const float y2 = Part[(size_t)i * 256 + j] + Part[262144 + (size_t)i * 256 + j];
    const float y3 = Part[(size_t)i * 256 + 128 + j] + Part[262144 + (size_t)i * 256 + 128 + j];
    const float y1 = Y1f[(size_t)i * 128 + j];
    const float s  = Sf[(size_t)i * 128 + j];
    const float g  = Gf[(size_t)i * 128 + j];
    const float u  = VU[(size_t)i * 256 + 128 + j];
    const float dA = -dlt[i] * expf(A_log[j]);
    const float bl = -0.1f * y1 + 0.01f * y2;
    const float cq = 0.005f * y3;
    float integ = 0.f;
    #pragma unroll
    for (int k = 0; k < 8; ++k) {
        const float t = c_t[k];
        integ += c_w[k] * (g + t * bl + t * t * cq) * expf(dA * t);
    }
    return u - 0.1f * s + integ;
}

// ---------------------------------------------------------------------------
// ew_mid: post(stage1) -> out[0] ; then pre(stage2) from zt + gelu(out1)
// ---------------------------------------------------------------------------
__global__ __launch_bounds__(128)
void ew_mid(const float* __restrict__ Part, const float* __restrict__ Gf,
            const float* __restrict__ Y1f, const float* __restrict__ Sf,
            const float* __restrict__ zt, const float* __restrict__ dlt1,
            const float* __restrict__ A1,
            const float* __restrict__ rms2, const float* __restrict__ W_B2,
            const float* __restrict__ b_B2, const float* __restrict__ W_dt,
            const float* __restrict__ b_dt, const float* __restrict__ A2,
            const float* __restrict__ m2, const int* __restrict__ act,
            float* __restrict__ VU, unsigned short* __restrict__ VUt,
            float* __restrict__ dlt2, float* __restrict__ out)
{
    const int i = blockIdx.x, j = threadIdx.x;
    __shared__ float xs[HDIM];
    __shared__ float red2[2];

    const float o1 = post_body(i, j, Part, Gf, Y1f, Sf, VU, dlt1, A1);
    out[(size_t)i * 128 + j] = o1;

    const float g3 = o1 * o1 * o1;
    const float gel = 0.5f * o1 * (1.0f + tanhf(0.7978845608028654f * (o1 + 0.044715f * g3)));
    const float x = zt[(size_t)i * 128 + j] + gel;

    pre_body(x, i, j, rms2, W_B2, b_B2, W_dt, b_dt, A2, m2, act,
             VU, VUt, dlt2, xs, red2);
}

// ---------------------------------------------------------------------------
// ew_tail: post(stage2) -> out[1]
// ---------------------------------------------------------------------------
__global__ __launch_bounds__(128)
void ew_tail(const float* __restrict__ Part, const float* __restrict__ Gf,
             const float* __restrict__ Y1f, const float* __restrict__ Sf,
             const float* __restrict__ VU, const float* __restrict__ dlt2,
             const float* __restrict__ A2, float* __restrict__ out)
{
    const int i = blockIdx.x, j = threadIdx.x;
    out[(size_t)i * 128 + j] = post_body(i, j, Part, Gf, Y1f, Sf, VU, dlt2, A2);
}

// ---------------------------------------------------------------------------
extern "C" void kernel_launch(void* const* d_in, const int* in_sizes, int n_in,
                              void* d_out, int out_size, void* d_ws, size_t ws_size,
                              hipStream_t stream)
{
    const float* L      = (const float*)d_in[0];
    const float* dL     = (const float*)d_in[1];
    const float* x_sub  = (const float*)d_in[2];
    const float* m1     = (const float*)d_in[3];
    const float* m2     = (const float*)d_in[4];
    const float* names  = (const float*)d_in[5];
    const float* rms1   = (const float*)d_in[6];
    const float* rms2   = (const float*)d_in[7];
    const float* W_tune = (const float*)d_in[8];
    const float* b_tune = (const float*)d_in[9];
    const float* W_B1   = (const float*)d_in[10];
    const float* b_B1   = (const float*)d_in[11];
    const float* W_B2   = (const float*)d_in[12];
    const float* b_B2   = (const float*)d_in[13];
    const float* W_dt   = (const float*)d_in[14];
    const float* b_dt   = (const float*)d_in[15];
    const float* A1     = (const float*)d_in[16];
    const float* A2     = (const float*)d_in[17];
    const int*   src    = (const int*)d_in[18];
    const int*   dst    = (const int*)d_in[19];
    const int*   act    = (const int*)d_in[20];
    float* out = (float*)d_out;

    // Workspace (~10.5 MB)
    float* ws   = (float*)d_ws;
    float* zt   = ws;                    // 131072
    float* VU   = zt   + 131072;         // 262144  fp32 [V|U]
    float* Gf   = VU   + 262144;         // 131072
    float* Y1f  = Gf   + 131072;         // 131072
    float* Sf   = Y1f  + 131072;         // 131072
    float* dlt1 = Sf   + 131072;         // 1024
    float* dlt2 = dlt1 + 1024;           // 1024
    float* Part = dlt2 + 1024;           // 524288 (GC partials, S=2)
    unsigned short* Lb    = (unsigned short*)(Part + 524288);   // 1048576
    unsigned short* dLb   = Lb    + 1048576;                    // 1048576
    unsigned short* VUt   = dLb   + 1048576;                    // 262144 [V|U]^T
    unsigned short* GTt   = VUt   + 262144;                     // 262144 [G|T]^T
    unsigned short* HY1t  = GTt   + 262144;                     // 262144 [H|Y1]^T

    conv_bf16<<<dim3(2048), dim3(256), 0, stream>>>(L, dL, Lb, dLb);

    ew_head<<<dim3(1024), dim3(128), 0, stream>>>(
        x_sub, names, src, dst, W_tune, b_tune,
        rms1, W_B1, b_B1, W_dt, b_dt, A1, m1, act,
        zt, VU, VUt, dlt1);

    // ---- stage 1 GEMM chain ----
    gemm_ga<<<dim3(4, 16), dim3(256), 0, stream>>>(Lb, dLb, VUt, VU, GTt, Gf);
    gemm_gb<<<dim3(6, 16), dim3(256), 0, stream>>>(Lb, dLb, GTt, HY1t, Y1f, Sf);
    gemm_gc<<<dim3(4, 16, 2), dim3(256), 0, stream>>>(dLb, HY1t, Part);

    ew_mid<<<dim3(1024), dim3(128), 0, stream>>>(
        Part, Gf, Y1f, Sf, zt, dlt1, A1,
        rms2, W_B2, b_B2, W_dt, b_dt, A2, m2, act,
        VU, VUt, dlt2, out);

    // ---- stage 2 GEMM chain ----
    gemm_ga<<<dim3(4, 16), dim3(256), 0, stream>>>(Lb, dLb, VUt, VU, GTt, Gf);
    gemm_gb<<<dim3(6, 16), dim3(256), 0, stream>>>(Lb, dLb, GTt, HY1t, Y1f, Sf);
    gemm_gc<<<dim3(4, 16, 2), dim3(256), 0, stream>>>(dLb, HY1t, Part);

    ew_tail<<<dim3(1024), dim3(128), 0, stream>>>(
        Part, Gf, Y1f, Sf, VU, dlt2, A2, out + 131072);
}

// Round 5
// 120.969 us; speedup vs baseline: 3.3828x; 1.0013x over previous
//
#include <hip/hip_runtime.h>
#include <math.h>

#define N_A   1024
#define HDIM  128
#define DIN   172
#define E_CNT 256
#define LP    72      // LDS pitch in bf16 elems

typedef __attribute__((ext_vector_type(8))) short bf16x8;
typedef __attribute__((ext_vector_type(4))) float f32x4;

__device__ __forceinline__ unsigned short f2bf(float x) {
    unsigned int u = __float_as_uint(x);
    unsigned int r = (u + 0x7fffu + ((u >> 16) & 1u)) >> 16;
    return (unsigned short)r;
}

// Gauss-Legendre nodes/weights mapped to [0,1] (tau=1)
__constant__ float c_t[8] = {
    0.4082826787521751f, 0.2372337950418355f, 0.10166676129318665f, 0.019855071751231843f,
    0.5917173212478249f, 0.7627662049581645f, 0.8983332387068134f, 0.9801449282487682f};
__constant__ float c_w[8] = {
    0.181341891689181f, 0.15685332293894365f, 0.11119051722668725f, 0.05061426814518815f,
    0.181341891689181f, 0.15685332293894365f, 0.11119051722668725f, 0.05061426814518815f};

// ---------------------------------------------------------------------------
// fp32 -> bf16 for L and dL (A operands, K-contiguous)
// ---------------------------------------------------------------------------
__global__ __launch_bounds__(256)
void conv_bf16(const float* __restrict__ L, const float* __restrict__ dL,
               unsigned short* __restrict__ Lb, unsigned short* __restrict__ dLb)
{
    const int t = blockIdx.x * 256 + threadIdx.x;      // 524288 threads, 4 elems each
    const float* src = (t < 262144) ? L : dL;
    unsigned short* dst = (t < 262144) ? Lb : dLb;
    const int q = (t < 262144) ? t : t - 262144;
    float4 v = *(const float4*)(src + (size_t)q * 4);
    ushort4 o;
    o.x = f2bf(v.x); o.y = f2bf(v.y); o.z = f2bf(v.z); o.w = f2bf(v.w);
    *(ushort4*)(dst + (size_t)q * 4) = o;
}

// ---------------------------------------------------------------------------
// wave-based 128-wide row reduction (2 waves per block)
// ---------------------------------------------------------------------------
__device__ __forceinline__ float rowsum128(float v, float* red2, int j)
{
    #pragma unroll
    for (int o = 32; o > 0; o >>= 1) v += __shfl_xor(v, o, 64);
    if ((j & 63) == 0) red2[j >> 6] = v;
    __syncthreads();
    const float t = red2[0] + red2[1];
    __syncthreads();
    return t;
}

// ---------------------------------------------------------------------------
// per-row "pre" body: rmsnorm -> delta -> Bz -> V,U ; writes VU/VUt/dlt
// ---------------------------------------------------------------------------
__device__ __forceinline__ void pre_body(
    float x, int i, int j,
    const float* __restrict__ rms_scale, const float* __restrict__ W_B,
    const float* __restrict__ b_B, const float* __restrict__ W_dt,
    const float* __restrict__ b_dt, const float* __restrict__ A_log,
    const float* __restrict__ m_vec, const int* __restrict__ act_ids,
    float* __restrict__ VU, unsigned short* __restrict__ VUt,
    float* __restrict__ dlt, float* xs, float* red2)
{
    const float ss = rowsum128(x * x, red2, j);
    const float rms = sqrtf(ss) * 0.08838834764831845f;   // /sqrt(128)
    const float xn = rms_scale[j] * x / (rms + 1e-8f);
    xs[j] = xn;
    const float dsum = rowsum128(xn * W_dt[j], red2, j);  // includes barrier for xs
    const float dd = dsum + b_dt[0];
    const float delta = dd > 0.f ? dd + log1pf(expf(-dd)) : log1pf(expf(dd));

    float acc = b_B[j];
    #pragma unroll 8
    for (int k = 0; k < HDIM; ++k) acc += xs[k] * W_B[k * HDIM + j];

    const float V = acc * delta;
    const int aid = act_ids[i];
    const float U = m_vec[(size_t)aid * HDIM + j] * expf(-delta * expf(A_log[j]));

    VU[(size_t)i * 256 + j] = V;
    VU[(size_t)i * 256 + 128 + j] = U;
    VUt[(size_t)j * 1024 + i] = f2bf(V);
    VUt[(size_t)(128 + j) * 1024 + i] = f2bf(U);
    if (j == 0) dlt[i] = delta;
}

// ---------------------------------------------------------------------------
// ew_head: zt = [x_sub|neigh]@W_tune + b_tune, then pre(stage 1)
// ---------------------------------------------------------------------------
__global__ __launch_bounds__(128)
void ew_head(const float* __restrict__ x_sub, const float* __restrict__ names,
             const int* __restrict__ src, const int* __restrict__ dst,
             const float* __restrict__ W_tune, const float* __restrict__ b_tune,
             const float* __restrict__ rms1, const float* __restrict__ W_B1,
             const float* __restrict__ b_B1, const float* __restrict__ W_dt,
             const float* __restrict__ b_dt, const float* __restrict__ A1,
             const float* __restrict__ m1, const int* __restrict__ act,
             float* __restrict__ zt, float* __restrict__ VU,
             unsigned short* __restrict__ VUt, float* __restrict__ dlt1)
{
    const int i = blockIdx.x, j = threadIdx.x;
    __shared__ float xl[DIN + 2];
    __shared__ float xs[HDIM];
    __shared__ float red2[2];

    for (int k = j; k < DIN; k += 128) xl[k] = x_sub[(size_t)i * DIN + k];
    if (j == 0) {
        float n0 = 0.f, n1 = 0.f;
        if (i < E_CNT)            { n0 = names[src[i]];          n1 = names[dst[i]]; }
        else if (i < 2 * E_CNT)   { n0 = names[dst[i - E_CNT]];  n1 = names[src[i - E_CNT]]; }
        xl[DIN] = n0; xl[DIN + 1] = n1;
    }
    __syncthreads();
    float acc = b_tune[j];
    #pragma unroll 2
    for (int k = 0; k < DIN + 2; ++k) acc += xl[k] * W_tune[k * HDIM + j];
    zt[(size_t)i * HDIM + j] = acc;

    pre_body(acc, i, j, rms1, W_B1, b_B1, W_dt, b_dt, A1, m1, act,
             VU, VUt, dlt1, xs, red2);
}

// ---------------------------------------------------------------------------
// GA: per slot (blockIdx.x): 0,1 -> type G (LV tile, cols slot*64 of V)
//                            2,3 -> type T (LU and dLU tiles, cols of U)
// epilogue: G = V - 0.1 LV -> GTt rows 0:128 (bf16 ^T) + Gf fp32
//           T = U - 0.1 LU - 0.05 dLU -> GTt rows 128:256
// ---------------------------------------------------------------------------
__global__ __launch_bounds__(256)
void gemm_ga(const unsigned short* __restrict__ Lb, const unsigned short* __restrict__ dLb,
             const unsigned short* __restrict__ VUt, const float* __restrict__ VU,
             unsigned short* __restrict__ GTt, float* __restrict__ Gf)
{
    const int slot = blockIdx.x, rb = blockIdx.y;
    const bool typeT = slot >= 2;
    const int cb = typeT ? slot - 2 : slot;
    const int bn0 = (typeT ? 128 : 0) + cb * 64;

    __shared__ unsigned short AsL[64 * LP];
    __shared__ unsigned short AsD[64 * LP];
    __shared__ unsigned short Bs[64 * LP];

    const int tid = threadIdx.x;
    const int srow = tid >> 2, skc = (tid & 3) << 4;

    const unsigned short* aL = Lb  + (size_t)(rb * 64 + srow) * 1024 + skc;
    const unsigned short* aD = dLb + (size_t)(rb * 64 + srow) * 1024 + skc;
    const unsigned short* bg = VUt + (size_t)(bn0 + srow) * 1024 + skc;

    const int lane = tid & 63, w = tid >> 6;
    const int wrow = (w >> 1) * 32, wcol = (w & 1) * 32;
    const int fr = lane & 15, fg = lane >> 4, fk = fg << 3;

    f32x4 acc[2][2] = {};
    f32x4 acc2[2][2] = {};

    bf16x8 pa0 = *(const bf16x8*)aL, pa1 = *(const bf16x8*)(aL + 8);
    bf16x8 pb0 = *(const bf16x8*)bg, pb1 = *(const bf16x8*)(bg + 8);
    bf16x8 pd0 = {}, pd1 = {};
    if (typeT) { pd0 = *(const bf16x8*)aD; pd1 = *(const bf16x8*)(aD + 8); }

    for (int k0 = 0; k0 < 1024; k0 += 64) {
        __syncthreads();
        *(bf16x8*)&AsL[srow * LP + skc] = pa0; *(bf16x8*)&AsL[srow * LP + skc + 8] = pa1;
        *(bf16x8*)&Bs[srow * LP + skc]  = pb0; *(bf16x8*)&Bs[srow * LP + skc + 8]  = pb1;
        if (typeT) { *(bf16x8*)&AsD[srow * LP + skc] = pd0; *(bf16x8*)&AsD[srow * LP + skc + 8] = pd1; }
        __syncthreads();
        if (k0 + 64 < 1024) {
            pa0 = *(const bf16x8*)(aL + k0 + 64); pa1 = *(const bf16x8*)(aL + k0 + 72);
            pb0 = *(const bf16x8*)(bg + k0 + 64); pb1 = *(const bf16x8*)(bg + k0 + 72);
            if (typeT) { pd0 = *(const bf16x8*)(aD + k0 + 64); pd1 = *(const bf16x8*)(aD + k0 + 72); }
        }
        #pragma unroll
        for (int h = 0; h < 2; ++h) {
            const int ko = h * 32 + fk;
            bf16x8 a0 = *(const bf16x8*)&AsL[(wrow + fr) * LP + ko];
            bf16x8 a1 = *(const bf16x8*)&AsL[(wrow + 16 + fr) * LP + ko];
            bf16x8 b0 = *(const bf16x8*)&Bs[(wcol + fr) * LP + ko];
            bf16x8 b1 = *(const bf16x8*)&Bs[(wcol + 16 + fr) * LP + ko];
            acc[0][0] = __builtin_amdgcn_mfma_f32_16x16x32_bf16(a0, b0, acc[0][0], 0, 0, 0);
            acc[0][1] = __builtin_amdgcn_mfma_f32_16x16x32_bf16(a0, b1, acc[0][1], 0, 0, 0);
            acc[1][0] = __builtin_amdgcn_mfma_f32_16x16x32_bf16(a1, b0, acc[1][0], 0, 0, 0);
            acc[1][1] = __builtin_amdgcn_mfma_f32_16x16x32_bf16(a1, b1, acc[1][1], 0, 0, 0);
            if (typeT) {
                bf16x8 d0 = *(const bf16x8*)&AsD[(wrow + fr) * LP + ko];
                bf16x8 d1 = *(const bf16x8*)&AsD[(wrow + 16 + fr) * LP + ko];
                acc2[0][0] = __builtin_amdgcn_mfma_f32_16x16x32_bf16(d0, b0, acc2[0][0], 0, 0, 0);
                acc2[0][1] = __builtin_amdgcn_mfma_f32_16x16x32_bf16(d0, b1, acc2[0][1], 0, 0, 0);
                acc2[1][0] = __builtin_amdgcn_mfma_f32_16x16x32_bf16(d1, b0, acc2[1][0], 0, 0, 0);
                acc2[1][1] = __builtin_amdgcn_mfma_f32_16x16x32_bf16(d1, b1, acc2[1][1], 0, 0, 0);
            }
        }
    }

    #pragma unroll
    for (int m = 0; m < 2; ++m) {
        const int gm = rb * 64 + wrow + m * 16 + fg * 4;
        #pragma unroll
        for (int n = 0; n < 2; ++n) {
            const int gj = cb * 64 + wcol + n * 16 + fr;   // 0..127
            float gv[4];
            #pragma unroll
            for (int r = 0; r < 4; ++r) {
                if (!typeT)
                    gv[r] = VU[(size_t)(gm + r) * 256 + gj] - 0.1f * acc[m][n][r];
                else
                    gv[r] = VU[(size_t)(gm + r) * 256 + 128 + gj]
                          - 0.1f * acc[m][n][r] - 0.05f * acc2[m][n][r];
            }
            ushort4 tv; tv.x = f2bf(gv[0]); tv.y = f2bf(gv[1]); tv.z = f2bf(gv[2]); tv.w = f2bf(gv[3]);
            *(ushort4*)&GTt[(size_t)((typeT ? 128 : 0) + gj) * 1024 + gm] = tv;
            if (!typeT) {
                #pragma unroll
                for (int r = 0; r < 4; ++r) Gf[(size_t)(gm + r) * 128 + gj] = gv[r];
            }
        }
    }
}

// ---------------------------------------------------------------------------
// single-A 64x64 MFMA core
// ---------------------------------------------------------------------------
__device__ __forceinline__ void core_sa(
    const unsigned short* __restrict__ ag, const unsigned short* __restrict__ bg,
    unsigned short* As, unsigned short* Bs, int klen,
    int srow, int skc, int wrow, int wcol, int fr, int fk, f32x4 (&acc)[2][2])
{
    bf16x8 pa0 = *(const bf16x8*)ag, pa1 = *(const bf16x8*)(ag + 8);
    bf16x8 pb0 = *(const bf16x8*)bg, pb1 = *(const bf16x8*)(bg + 8);
    for (int k0 = 0; k0 < klen; k0 += 64) {
        __syncthreads();
        *(bf16x8*)&As[srow * LP + skc] = pa0; *(bf16x8*)&As[srow * LP + skc + 8] = pa1;
        *(bf16x8*)&Bs[srow * LP + skc] = pb0; *(bf16x8*)&Bs[srow * LP + skc + 8] = pb1;
        __syncthreads();
        if (k0 + 64 < klen) {
            pa0 = *(const bf16x8*)(ag + k0 + 64); pa1 = *(const bf16x8*)(ag + k0 + 72);
            pb0 = *(const bf16x8*)(bg + k0 + 64); pb1 = *(const bf16x8*)(bg + k0 + 72);
        }
        #pragma unroll
        for (int h = 0; h < 2; ++h) {
            const int ko = h * 32 + fk;
            bf16x8 a0 = *(const bf16x8*)&As[(wrow + fr) * LP + ko];
            bf16x8 a1 = *(const bf16x8*)&As[(wrow + 16 + fr) * LP + ko];
            bf16x8 b0 = *(const bf16x8*)&Bs[(wcol + fr) * LP + ko];
            bf16x8 b1 = *(const bf16x8*)&Bs[(wcol + 16 + fr) * LP + ko];
            acc[0][0] = __builtin_amdgcn_mfma_f32_16x16x32_bf16(a0, b0, acc[0][0], 0, 0, 0);
            acc[0][1] = __builtin_amdgcn_mfma_f32_16x16x32_bf16(a0, b1, acc[0][1], 0, 0, 0);
            acc[1][0] = __builtin_amdgcn_mfma_f32_16x16x32_bf16(a1, b0, acc[1][0], 0, 0, 0);
            acc[1][1] = __builtin_amdgcn_mfma_f32_16x16x32_bf16(a1, b1, acc[1][1], 0, 0, 0);
        }
    }
}

// ---------------------------------------------------------------------------
// GB: slots 0,1: H = L@G   -> HY1t rows 0:128 (bf16 ^T)
//     slots 2,3: Y1 = dL@G -> HY1t rows 128:256 + Y1f fp32
//     slots 4,5: S = dL@T  -> Sf fp32
// ---------------------------------------------------------------------------
__global__ __launch_bounds__(256)
void gemm_gb(const unsigned short* __restrict__ Lb, const unsigned short* __restrict__ dLb,
             const unsigned short* __restrict__ GTt,
             unsigned short* __restrict__ HY1t, float* __restrict__ Y1f,
             float* __restrict__ Sf)
{
    const int slot = blockIdx.x, rb = blockIdx.y;
    const unsigned short* A = (slot < 2) ? Lb : dLb;
    const int jbase = ((slot < 2) ? slot : (slot < 4) ? slot - 2 : slot - 4) * 64;
    const int bn0 = (slot < 4) ? jbase : 128 + jbase;

    __shared__ unsigned short As[64 * LP];
    __shared__ unsigned short Bs[64 * LP];

    const int tid = threadIdx.x;
    const int srow = tid >> 2, skc = (tid & 3) << 4;
    const unsigned short* ag = A   + (size_t)(rb * 64 + srow) * 1024 + skc;
    const unsigned short* bg = GTt + (size_t)(bn0 + srow) * 1024 + skc;

    const int lane = tid & 63, w = tid >> 6;
    const int wrow = (w >> 1) * 32, wcol = (w & 1) * 32;
    const int fr = lane & 15, fg = lane >> 4, fk = fg << 3;

    f32x4 acc[2][2] = {};
    core_sa(ag, bg, As, Bs, 1024, srow, skc, wrow, wcol, fr, fk, acc);

    #pragma unroll
    for (int m = 0; m < 2; ++m) {
        const int gm = rb * 64 + wrow + m * 16 + fg * 4;
        #pragma unroll
        for (int n = 0; n < 2; ++n) {
            const int gj = jbase + wcol + n * 16 + fr;
            if (slot < 4) {
                ushort4 tv;
                tv.x = f2bf(acc[m][n][0]); tv.y = f2bf(acc[m][n][1]);
                tv.z = f2bf(acc[m][n][2]); tv.w = f2bf(acc[m][n][3]);
                *(ushort4*)&HY1t[(size_t)((slot < 2 ? 0 : 128) + gj) * 1024 + gm] = tv;
                if (slot >= 2) {
                    #pragma unroll
                    for (int r = 0; r < 4; ++r) Y1f[(size_t)(gm + r) * 128 + gj] = acc[m][n][r];
                }
            } else {
                #pragma unroll
                for (int r = 0; r < 4; ++r) Sf[(size_t)(gm + r) * 128 + gj] = acc[m][n][r];
            }
        }
    }
}

// ---------------------------------------------------------------------------
// GC: dL @ [H|Y1]  (N=256), split-K S=2 -> Part fp32 partials [s][1024][256]
// ---------------------------------------------------------------------------
__global__ __launch_bounds__(256)
void gemm_gc(const unsigned short* __restrict__ dLb, const unsigned short* __restrict__ HY1t,
             float* __restrict__ Part)
{
    const int cb = blockIdx.x, rb = blockIdx.y, sz = blockIdx.z;
    const int kbase = sz * 512;

    __shared__ unsigned short As[64 * LP];
    __shared__ unsigned short Bs[64 * LP];

    const int tid = threadIdx.x;
    const int srow = tid >> 2, skc = (tid & 3) << 4;
    const unsigned short* ag = dLb  + (size_t)(rb * 64 + srow) * 1024 + kbase + skc;
    const unsigned short* bg = HY1t + (size_t)(cb * 64 + srow) * 1024 + kbase + skc;

    const int lane = tid & 63, w = tid >> 6;
    const int wrow = (w >> 1) * 32, wcol = (w & 1) * 32;
    const int fr = lane & 15, fg = lane >> 4, fk = fg << 3;

    f32x4 acc[2][2] = {};
    core_sa(ag, bg, As, Bs, 512, srow, skc, wrow, wcol, fr, fk, acc);

    float* Cb = Part + (size_t)sz * 262144;
    #pragma unroll
    for (int m = 0; m < 2; ++m) {
        const int gm = rb * 64 + wrow + m * 16 + fg * 4;
        #pragma unroll
        for (int n = 0; n < 2; ++n) {
            const int gn = cb * 64 + wcol + n * 16 + fr;
            #pragma unroll
            for (int r = 0; r < 4; ++r) Cb[(size_t)(gm + r) * 256 + gn] = acc[m][n][r];
        }
    }
}

// ---------------------------------------------------------------------------
// post body: out = U - 0.1 S + sum_k w_k (G + t(-0.1 Y1 + 0.01 Y2) + 0.005 t^2 Y3) e^{dA t}
// ---------------------------------------------------------------------------
__device__ __forceinline__ float post_body(
    int i, int j, const float* __restrict__ Part, const float* __restrict__ Gf,
    const float* __restrict__ Y1f, const float* __restrict__ Sf,
    const float* __restrict__ VU, const float* __restrict__ dlt,
    const float* __restrict__ A_log)
{
    const float y2 = Part[(size_t)i * 256 + j] + Part[262144 + (size_t)i * 256 + j];
    const float y3 = Part[(size_t)i * 256 + 128 + j] + Part[262144 + (size_t)i * 256 + 128 + j];
    const float y1 = Y1f[(size_t)i * 128 + j];
    const float s  = Sf[(size_t)i * 128 + j];
    const float g  = Gf[(size_t)i * 128 + j];
    const float u  = VU[(size_t)i * 256 + 128 + j];
    const float dA = -dlt[i] * expf(A_log[j]);
    const float bl = -0.1f * y1 + 0.01f * y2;
    const float cq = 0.005f * y3;
    float integ = 0.f;
    #pragma unroll
    for (int k = 0; k < 8; ++k) {
        const float t = c_t[k];
        integ += c_w[k] * (g + t * bl + t * t * cq) * expf(dA * t);
    }
    return u - 0.1f * s + integ;
}

// ---------------------------------------------------------------------------
// ew_mid: post(stage1) -> out[0] ; then pre(stage2) from zt + gelu(out1)
// ---------------------------------------------------------------------------
__global__ __launch_bounds__(128)
void ew_mid(const float* __restrict__ Part, const float* __restrict__ Gf,
            const float* __restrict__ Y1f, const float* __restrict__ Sf,
            const float* __restrict__ zt, const float* __restrict__ dlt1,
            const float* __restrict__ A1,
            const float* __restrict__ rms2, const float* __restrict__ W_B2,
            const float* __restrict__ b_B2, const float* __restrict__ W_dt,
            const float* __restrict__ b_dt, const float* __restrict__ A2,
            const float* __restrict__ m2, const int* __restrict__ act,
            float* __restrict__ VU, unsigned short* __restrict__ VUt,
            float* __restrict__ dlt2, float* __restrict__ out)
{
    const int i = blockIdx.x, j = threadIdx.x;
    __shared__ float xs[HDIM];
    __shared__ float red2[2];

    const float o1 = post_body(i, j, Part, Gf, Y1f, Sf, VU, dlt1, A1);
    out[(size_t)i * 128 + j] = o1;

    const float g3 = o1 * o1 * o1;
    const float gel = 0.5f * o1 * (1.0f + tanhf(0.7978845608028654f * (o1 + 0.044715f * g3)));
    const float x = zt[(size_t)i * 128 + j] + gel;

    pre_body(x, i, j, rms2, W_B2, b_B2, W_dt, b_dt, A2, m2, act,
             VU, VUt, dlt2, xs, red2);
}

// ---------------------------------------------------------------------------
// ew_tail: post(stage2) -> out[1]
// ---------------------------------------------------------------------------
__global__ __launch_bounds__(128)
void ew_tail(const float* __restrict__ Part, const float* __restrict__ Gf,
             const float* __restrict__ Y1f, const float* __restrict__ Sf,
             const float* __restrict__ VU, const float* __restrict__ dlt2,
             const float* __restrict__ A2, float* __restrict__ out)
{
    const int i = blockIdx.x, j = threadIdx.x;
    out[(size_t)i * 128 + j] = post_body(i, j, Part, Gf, Y1f, Sf, VU, dlt2, A2);
}

// ---------------------------------------------------------------------------
extern "C" void kernel_launch(void* const* d_in, const int* in_sizes, int n_in,
                              void* d_out, int out_size, void* d_ws, size_t ws_size,
                              hipStream_t stream)
{
    const float* L      = (const float*)d_in[0];
    const float* dL     = (const float*)d_in[1];
    const float* x_sub  = (const float*)d_in[2];
    const float* m1     = (const float*)d_in[3];
    const float* m2     = (const float*)d_in[4];
    const float* names  = (const float*)d_in[5];
    const float* rms1   = (const float*)d_in[6];
    const float* rms2   = (const float*)d_in[7];
    const float* W_tune = (const float*)d_in[8];
    const float* b_tune = (const float*)d_in[9];
    const float* W_B1   = (const float*)d_in[10];
    const float* b_B1   = (const float*)d_in[11];
    const float* W_B2   = (const float*)d_in[12];
    const float* b_B2   = (const float*)d_in[13];
    const float* W_dt   = (const float*)d_in[14];
    const float* b_dt   = (const float*)d_in[15];
    const float* A1     = (const float*)d_in[16];
    const float* A2     = (const float*)d_in[17];
    const int*   src    = (const int*)d_in[18];
    const int*   dst    = (const int*)d_in[19];
    const int*   act    = (const int*)d_in[20];
    float* out = (float*)d_out;

    // Workspace (~10.5 MB)
    float* ws   = (float*)d_ws;
    float* zt   = ws;                    // 131072
    float* VU   = zt   + 131072;         // 262144  fp32 [V|U]
    float* Gf   = VU   + 262144;         // 131072
    float* Y1f  = Gf   + 131072;         // 131072
    float* Sf   = Y1f  + 131072;         // 131072
    float* dlt1 = Sf   + 131072;         // 1024
    float* dlt2 = dlt1 + 1024;           // 1024
    float* Part = dlt2 + 1024;           // 524288 (GC partials, S=2)
    unsigned short* Lb    = (unsigned short*)(Part + 524288);   // 1048576
    unsigned short* dLb   = Lb    + 1048576;                    // 1048576
    unsigned short* VUt   = dLb   + 1048576;                    // 262144 [V|U]^T
    unsigned short* GTt   = VUt   + 262144;                     // 262144 [G|T]^T
    unsigned short* HY1t  = GTt   + 262144;                     // 262144 [H|Y1]^T

    conv_bf16<<<dim3(2048), dim3(256), 0, stream>>>(L, dL, Lb, dLb);

    ew_head<<<dim3(1024), dim3(128), 0, stream>>>(
        x_sub, names, src, dst, W_tune, b_tune,
        rms1, W_B1, b_B1, W_dt, b_dt, A1, m1, act,
        zt, VU, VUt, dlt1);

    // ---- stage 1 GEMM chain ----
    gemm_ga<<<dim3(4, 16), dim3(256), 0, stream>>>(Lb, dLb, VUt, VU, GTt, Gf);
    gemm_gb<<<dim3(6, 16), dim3(256), 0, stream>>>(Lb, dLb, GTt, HY1t, Y1f, Sf);
    gemm_gc<<<dim3(4, 16, 2), dim3(256), 0, stream>>>(dLb, HY1t, Part);

    ew_mid<<<dim3(1024), dim3(128), 0, stream>>>(
        Part, Gf, Y1f, Sf, zt, dlt1, A1,
        rms2, W_B2, b_B2, W_dt, b_dt, A2, m2, act,
        VU, VUt, dlt2, out);

    // ---- stage 2 GEMM chain ----
    gemm_ga<<<dim3(4, 16), dim3(256), 0, stream>>>(Lb, dLb, VUt, VU, GTt, Gf);
    gemm_gb<<<dim3(6, 16), dim3(256), 0, stream>>>(Lb, dLb, GTt, HY1t, Y1f, Sf);
    gemm_gc<<<dim3(4, 16, 2), dim3(256), 0, stream>>>(dLb, HY1t, Part);

    ew_tail<<<dim3(1024), dim3(128), 0, stream>>>(
        Part, Gf, Y1f, Sf, VU, dlt2, A2, out + 131072);
}

// Round 6
// 120.589 us; speedup vs baseline: 3.3935x; 1.0032x over previous
//
#include <hip/hip_runtime.h>
#include <math.h>

#define N_A   1024
#define HDIM  128
#define DIN   172
#define E_CNT 256
#define LP    72      // LDS pitch in bf16 elems

typedef __attribute__((ext_vector_type(8))) short bf16x8;
typedef __attribute__((ext_vector_type(4))) float f32x4;

__device__ __forceinline__ unsigned short f2bf(float x) {
    unsigned int u = __float_as_uint(x);
    unsigned int r = (u + 0x7fffu + ((u >> 16) & 1u)) >> 16;
    return (unsigned short)r;
}

// Gauss-Legendre nodes/weights mapped to [0,1] (tau=1)
__constant__ float c_t[8] = {
    0.4082826787521751f, 0.2372337950418355f, 0.10166676129318665f, 0.019855071751231843f,
    0.5917173212478249f, 0.7627662049581645f, 0.8983332387068134f, 0.9801449282487682f};
__constant__ float c_w[8] = {
    0.181341891689181f, 0.15685332293894365f, 0.11119051722668725f, 0.05061426814518815f,
    0.181341891689181f, 0.15685332293894365f, 0.11119051722668725f, 0.05061426814518815f};

// ---------------------------------------------------------------------------
// fp32 -> bf16 for L and dL (A operands, K-contiguous)
// ---------------------------------------------------------------------------
__global__ __launch_bounds__(256)
void conv_bf16(const float* __restrict__ L, const float* __restrict__ dL,
               unsigned short* __restrict__ Lb, unsigned short* __restrict__ dLb)
{
    const int t = blockIdx.x * 256 + threadIdx.x;      // 524288 threads, 4 elems each
    const float* src = (t < 262144) ? L : dL;
    unsigned short* dst = (t < 262144) ? Lb : dLb;
    const int q = (t < 262144) ? t : t - 262144;
    float4 v = *(const float4*)(src + (size_t)q * 4);
    ushort4 o;
    o.x = f2bf(v.x); o.y = f2bf(v.y); o.z = f2bf(v.z); o.w = f2bf(v.w);
    *(ushort4*)(dst + (size_t)q * 4) = o;
}

// ---------------------------------------------------------------------------
// wave-based 128-wide row reduction (2 waves per block)
// ---------------------------------------------------------------------------
__device__ __forceinline__ float rowsum128(float v, float* red2, int j)
{
    #pragma unroll
    for (int o = 32; o > 0; o >>= 1) v += __shfl_xor(v, o, 64);
    if ((j & 63) == 0) red2[j >> 6] = v;
    __syncthreads();
    const float t = red2[0] + red2[1];
    __syncthreads();
    return t;
}

// ---------------------------------------------------------------------------
// per-row "pre" body: rmsnorm -> delta -> Bz -> V,U ; writes VU/VUt/dlt
// ---------------------------------------------------------------------------
__device__ __forceinline__ void pre_body(
    float x, int i, int j,
    const float* __restrict__ rms_scale, const float* __restrict__ W_B,
    const float* __restrict__ b_B, const float* __restrict__ W_dt,
    const float* __restrict__ b_dt, const float* __restrict__ A_log,
    const float* __restrict__ m_vec, const int* __restrict__ act_ids,
    float* __restrict__ VU, unsigned short* __restrict__ VUt,
    float* __restrict__ dlt, float* xs, float* red2)
{
    const float ss = rowsum128(x * x, red2, j);
    const float rms = sqrtf(ss) * 0.08838834764831845f;   // /sqrt(128)
    const float xn = rms_scale[j] * x / (rms + 1e-8f);
    xs[j] = xn;
    const float dsum = rowsum128(xn * W_dt[j], red2, j);  // includes barrier for xs
    const float dd = dsum + b_dt[0];
    const float delta = dd > 0.f ? dd + log1pf(expf(-dd)) : log1pf(expf(dd));

    float acc = b_B[j];
    #pragma unroll 8
    for (int k = 0; k < HDIM; ++k) acc += xs[k] * W_B[k * HDIM + j];

    const float V = acc * delta;
    const int aid = act_ids[i];
    const float U = m_vec[(size_t)aid * HDIM + j] * expf(-delta * expf(A_log[j]));

    VU[(size_t)i * 256 + j] = V;
    VU[(size_t)i * 256 + 128 + j] = U;
    VUt[(size_t)j * 1024 + i] = f2bf(V);
    VUt[(size_t)(128 + j) * 1024 + i] = f2bf(U);
    if (j == 0) dlt[i] = delta;
}

// ---------------------------------------------------------------------------
// ew_head: zt = [x_sub|neigh]@W_tune + b_tune, then pre(stage 1)
// ---------------------------------------------------------------------------
__global__ __launch_bounds__(128)
void ew_head(const float* __restrict__ x_sub, const float* __restrict__ names,
             const int* __restrict__ src, const int* __restrict__ dst,
             const float* __restrict__ W_tune, const float* __restrict__ b_tune,
             const float* __restrict__ rms1, const float* __restrict__ W_B1,
             const float* __restrict__ b_B1, const float* __restrict__ W_dt,
             const float* __restrict__ b_dt, const float* __restrict__ A1,
             const float* __restrict__ m1, const int* __restrict__ act,
             float* __restrict__ zt, float* __restrict__ VU,
             unsigned short* __restrict__ VUt, float* __restrict__ dlt1)
{
    const int i = blockIdx.x, j = threadIdx.x;
    __shared__ float xl[DIN + 2];
    __shared__ float xs[HDIM];
    __shared__ float red2[2];

    for (int k = j; k < DIN; k += 128) xl[k] = x_sub[(size_t)i * DIN + k];
    if (j == 0) {
        float n0 = 0.f, n1 = 0.f;
        if (i < E_CNT)            { n0 = names[src[i]];          n1 = names[dst[i]]; }
        else if (i < 2 * E_CNT)   { n0 = names[dst[i - E_CNT]];  n1 = names[src[i - E_CNT]]; }
        xl[DIN] = n0; xl[DIN + 1] = n1;
    }
    __syncthreads();
    float acc = b_tune[j];
    #pragma unroll 2
    for (int k = 0; k < DIN + 2; ++k) acc += xl[k] * W_tune[k * HDIM + j];
    zt[(size_t)i * HDIM + j] = acc;

    pre_body(acc, i, j, rms1, W_B1, b_B1, W_dt, b_dt, A1, m1, act,
             VU, VUt, dlt1, xs, red2);
}

// ---------------------------------------------------------------------------
// GA: per slot (blockIdx.x): 0,1 -> type G (LV tile, cols slot*64 of V)
//                            2,3 -> type T (LU and dLU tiles, cols of U)
// epilogue: G = V - 0.1 LV -> GTt rows 0:128 (bf16 ^T) + Gf fp32
//           T = U - 0.1 LU - 0.05 dLU -> GTt rows 128:256
// ---------------------------------------------------------------------------
__global__ __launch_bounds__(256)
void gemm_ga(const unsigned short* __restrict__ Lb, const unsigned short* __restrict__ dLb,
             const unsigned short* __restrict__ VUt, const float* __restrict__ VU,
             unsigned short* __restrict__ GTt, float* __restrict__ Gf)
{
    const int slot = blockIdx.x, rb = blockIdx.y;
    const bool typeT = slot >= 2;
    const int cb = typeT ? slot - 2 : slot;
    const int bn0 = (typeT ? 128 : 0) + cb * 64;

    __shared__ unsigned short AsL[64 * LP];
    __shared__ unsigned short AsD[64 * LP];
    __shared__ unsigned short Bs[64 * LP];

    const int tid = threadIdx.x;
    const int srow = tid >> 2, skc = (tid & 3) << 4;

    const unsigned short* aL = Lb  + (size_t)(rb * 64 + srow) * 1024 + skc;
    const unsigned short* aD = dLb + (size_t)(rb * 64 + srow) * 1024 + skc;
    const unsigned short* bg = VUt + (size_t)(bn0 + srow) * 1024 + skc;

    const int lane = tid & 63, w = tid >> 6;
    const int wrow = (w >> 1) * 32, wcol = (w & 1) * 32;
    const int fr = lane & 15, fg = lane >> 4, fk = fg << 3;

    f32x4 acc[2][2] = {};
    f32x4 acc2[2][2] = {};

    bf16x8 pa0 = *(const bf16x8*)aL, pa1 = *(const bf16x8*)(aL + 8);
    bf16x8 pb0 = *(const bf16x8*)bg, pb1 = *(const bf16x8*)(bg + 8);
    bf16x8 pd0 = {}, pd1 = {};
    if (typeT) { pd0 = *(const bf16x8*)aD; pd1 = *(const bf16x8*)(aD + 8); }

    for (int k0 = 0; k0 < 1024; k0 += 64) {
        __syncthreads();
        *(bf16x8*)&AsL[srow * LP + skc] = pa0; *(bf16x8*)&AsL[srow * LP + skc + 8] = pa1;
        *(bf16x8*)&Bs[srow * LP + skc]  = pb0; *(bf16x8*)&Bs[srow * LP + skc + 8]  = pb1;
        if (typeT) { *(bf16x8*)&AsD[srow * LP + skc] = pd0; *(bf16x8*)&AsD[srow * LP + skc + 8] = pd1; }
        __syncthreads();
        if (k0 + 64 < 1024) {
            pa0 = *(const bf16x8*)(aL + k0 + 64); pa1 = *(const bf16x8*)(aL + k0 + 72);
            pb0 = *(const bf16x8*)(bg + k0 + 64); pb1 = *(const bf16x8*)(bg + k0 + 72);
            if (typeT) { pd0 = *(const bf16x8*)(aD + k0 + 64); pd1 = *(const bf16x8*)(aD + k0 + 72); }
        }
        #pragma unroll
        for (int h = 0; h < 2; ++h) {
            const int ko = h * 32 + fk;
            bf16x8 a0 = *(const bf16x8*)&AsL[(wrow + fr) * LP + ko];
            bf16x8 a1 = *(const bf16x8*)&AsL[(wrow + 16 + fr) * LP + ko];
            bf16x8 b0 = *(const bf16x8*)&Bs[(wcol + fr) * LP + ko];
            bf16x8 b1 = *(const bf16x8*)&Bs[(wcol + 16 + fr) * LP + ko];
            acc[0][0] = __builtin_amdgcn_mfma_f32_16x16x32_bf16(a0, b0, acc[0][0], 0, 0, 0);
            acc[0][1] = __builtin_amdgcn_mfma_f32_16x16x32_bf16(a0, b1, acc[0][1], 0, 0, 0);
            acc[1][0] = __builtin_amdgcn_mfma_f32_16x16x32_bf16(a1, b0, acc[1][0], 0, 0, 0);
            acc[1][1] = __builtin_amdgcn_mfma_f32_16x16x32_bf16(a1, b1, acc[1][1], 0, 0, 0);
            if (typeT) {
                bf16x8 d0 = *(const bf16x8*)&AsD[(wrow + fr) * LP + ko];
                bf16x8 d1 = *(const bf16x8*)&AsD[(wrow + 16 + fr) * LP + ko];
                acc2[0][0] = __builtin_amdgcn_mfma_f32_16x16x32_bf16(d0, b0, acc2[0][0], 0, 0, 0);
                acc2[0][1] = __builtin_amdgcn_mfma_f32_16x16x32_bf16(d0, b1, acc2[0][1], 0, 0, 0);
                acc2[1][0] = __builtin_amdgcn_mfma_f32_16x16x32_bf16(d1, b0, acc2[1][0], 0, 0, 0);
                acc2[1][1] = __builtin_amdgcn_mfma_f32_16x16x32_bf16(d1, b1, acc2[1][1], 0, 0, 0);
            }
        }
    }

    #pragma unroll
    for (int m = 0; m < 2; ++m) {
        const int gm = rb * 64 + wrow + m * 16 + fg * 4;
        #pragma unroll
        for (int n = 0; n < 2; ++n) {
            const int gj = cb * 64 + wcol + n * 16 + fr;   // 0..127
            float gv[4];
            #pragma unroll
            for (int r = 0; r < 4; ++r) {
                if (!typeT)
                    gv[r] = VU[(size_t)(gm + r) * 256 + gj] - 0.1f * acc[m][n][r];
                else
                    gv[r] = VU[(size_t)(gm + r) * 256 + 128 + gj]
                          - 0.1f * acc[m][n][r] - 0.05f * acc2[m][n][r];
            }
            ushort4 tv; tv.x = f2bf(gv[0]); tv.y = f2bf(gv[1]); tv.z = f2bf(gv[2]); tv.w = f2bf(gv[3]);
            *(ushort4*)&GTt[(size_t)((typeT ? 128 : 0) + gj) * 1024 + gm] = tv;
            if (!typeT) {
                #pragma unroll
                for (int r = 0; r < 4; ++r) Gf[(size_t)(gm + r) * 128 + gj] = gv[r];
            }
        }
    }
}

// ---------------------------------------------------------------------------
// single-A 64x64 MFMA core
// ---------------------------------------------------------------------------
__device__ __forceinline__ void core_sa(
    const unsigned short* __restrict__ ag, const unsigned short* __restrict__ bg,
    unsigned short* As, unsigned short* Bs, int klen,
    int srow, int skc, int wrow, int wcol, int fr, int fk, f32x4 (&acc)[2][2])
{
    bf16x8 pa0 = *(const bf16x8*)ag, pa1 = *(const bf16x8*)(ag + 8);
    bf16x8 pb0 = *(const bf16x8*)bg, pb1 = *(const bf16x8*)(bg + 8);
    for (int k0 = 0; k0 < klen; k0 += 64) {
        __syncthreads();
        *(bf16x8*)&As[srow * LP + skc] = pa0; *(bf16x8*)&As[srow * LP + skc + 8] = pa1;
        *(bf16x8*)&Bs[srow * LP + skc] = pb0; *(bf16x8*)&Bs[srow * LP + skc + 8] = pb1;
        __syncthreads();
        if (k0 + 64 < klen) {
            pa0 = *(const bf16x8*)(ag + k0 + 64); pa1 = *(const bf16x8*)(ag + k0 + 72);
            pb0 = *(const bf16x8*)(bg + k0 + 64); pb1 = *(const bf16x8*)(bg + k0 + 72);
        }
        #pragma unroll
        for (int h = 0; h < 2; ++h) {
            const int ko = h * 32 + fk;
            bf16x8 a0 = *(const bf16x8*)&As[(wrow + fr) * LP + ko];
            bf16x8 a1 = *(const bf16x8*)&As[(wrow + 16 + fr) * LP + ko];
            bf16x8 b0 = *(const bf16x8*)&Bs[(wcol + fr) * LP + ko];
            bf16x8 b1 = *(const bf16x8*)&Bs[(wcol + 16 + fr) * LP + ko];
            acc[0][0] = __builtin_amdgcn_mfma_f32_16x16x32_bf16(a0, b0, acc[0][0], 0, 0, 0);
            acc[0][1] = __builtin_amdgcn_mfma_f32_16x16x32_bf16(a0, b1, acc[0][1], 0, 0, 0);
            acc[1][0] = __builtin_amdgcn_mfma_f32_16x16x32_bf16(a1, b0, acc[1][0], 0, 0, 0);
            acc[1][1] = __builtin_amdgcn_mfma_f32_16x16x32_bf16(a1, b1, acc[1][1], 0, 0, 0);
        }
    }
}

// ---------------------------------------------------------------------------
// GB: slots 0,1: H = L@G   -> HY1t rows 0:128 (bf16 ^T)
//     slots 2,3: Y1 = dL@G -> HY1t rows 128:256 + Y1f fp32
//     slots 4,5: S = dL@T  -> Sf fp32
// ---------------------------------------------------------------------------
__global__ __launch_bounds__(256)
void gemm_gb(const unsigned short* __restrict__ Lb, const unsigned short* __restrict__ dLb,
             const unsigned short* __restrict__ GTt,
             unsigned short* __restrict__ HY1t, float* __restrict__ Y1f,
             float* __restrict__ Sf)
{
    const int slot = blockIdx.x, rb = blockIdx.y;
    const unsigned short* A = (slot < 2) ? Lb : dLb;
    const int jbase = ((slot < 2) ? slot : (slot < 4) ? slot - 2 : slot - 4) * 64;
    const int bn0 = (slot < 4) ? jbase : 128 + jbase;

    __shared__ unsigned short As[64 * LP];
    __shared__ unsigned short Bs[64 * LP];

    const int tid = threadIdx.x;
    const int srow = tid >> 2, skc = (tid & 3) << 4;
    const unsigned short* ag = A   + (size_t)(rb * 64 + srow) * 1024 + skc;
    const unsigned short* bg = GTt + (size_t)(bn0 + srow) * 1024 + skc;

    const int lane = tid & 63, w = tid >> 6;
    const int wrow = (w >> 1) * 32, wcol = (w & 1) * 32;
    const int fr = lane & 15, fg = lane >> 4, fk = fg << 3;

    f32x4 acc[2][2] = {};
    core_sa(ag, bg, As, Bs, 1024, srow, skc, wrow, wcol, fr, fk, acc);

    #pragma unroll
    for (int m = 0; m < 2; ++m) {
        const int gm = rb * 64 + wrow + m * 16 + fg * 4;
        #pragma unroll
        for (int n = 0; n < 2; ++n) {
            const int gj = jbase + wcol + n * 16 + fr;
            if (slot < 4) {
                ushort4 tv;
                tv.x = f2bf(acc[m][n][0]); tv.y = f2bf(acc[m][n][1]);
                tv.z = f2bf(acc[m][n][2]); tv.w = f2bf(acc[m][n][3]);
                *(ushort4*)&HY1t[(size_t)((slot < 2 ? 0 : 128) + gj) * 1024 + gm] = tv;
                if (slot >= 2) {
                    #pragma unroll
                    for (int r = 0; r < 4; ++r) Y1f[(size_t)(gm + r) * 128 + gj] = acc[m][n][r];
                }
            } else {
                #pragma unroll
                for (int r = 0; r < 4; ++r) Sf[(size_t)(gm + r) * 128 + gj] = acc[m][n][r];
            }
        }
    }
}

// ---------------------------------------------------------------------------
// GC: dL @ [H|Y1]  (N=256), split-K S=2 -> Part fp32 partials [s][1024][256]
// ---------------------------------------------------------------------------
__global__ __launch_bounds__(256)
void gemm_gc(const unsigned short* __restrict__ dLb, const unsigned short* __restrict__ HY1t,
             float* __restrict__ Part)
{
    const int cb = blockIdx.x, rb = blockIdx.y, sz = blockIdx.z;
    const int kbase = sz * 512;

    __shared__ unsigned short As[64 * LP];
    __shared__ unsigned short Bs[64 * LP];

    const int tid = threadIdx.x;
    const int srow = tid >> 2, skc = (tid & 3) << 4;
    const unsigned short* ag = dLb  + (size_t)(rb * 64 + srow) * 1024 + kbase + skc;
    const unsigned short* bg = HY1t + (size_t)(cb * 64 + srow) * 1024 + kbase + skc;

    const int lane = tid & 63, w = tid >> 6;
    const int wrow = (w >> 1) * 32, wcol = (w & 1) * 32;
    const int fr = lane & 15, fg = lane >> 4, fk = fg << 3;

    f32x4 acc[2][2] = {};
    core_sa(ag, bg, As, Bs, 512, srow, skc, wrow, wcol, fr, fk, acc);

    float* Cb = Part + (size_t)sz * 262144;
    #pragma unroll
    for (int m = 0; m < 2; ++m) {
        const int gm = rb * 64 + wrow + m * 16 + fg * 4;
        #pragma unroll
        for (int n = 0; n < 2; ++n) {
            const int gn = cb * 64 + wcol + n * 16 + fr;
            #pragma unroll
            for (int r = 0; r < 4; ++r) Cb[(size_t)(gm + r) * 256 + gn] = acc[m][n][r];
        }
    }
}

// ---------------------------------------------------------------------------
// post body: out = U - 0.1 S + sum_k w_k (G + t(-0.1 Y1 + 0.01 Y2) + 0.005 t^2 Y3) e^{dA t}
// ---------------------------------------------------------------------------
__device__ __forceinline__ float post_body(
    int i, int j, const float* __restrict__ Part, const float* __restrict__ Gf,
    const float* __restrict__ Y1f, const float* __restrict__ Sf,
    const float* __restrict__ VU, const float* __restrict__ dlt,
    const float* __restrict__ A_log)
{
    const float y2 = Part[(size_t)i * 256 + j] + Part[262144 + (size_t)i * 256 + j];
    const float y3 = Part[(size_t)i * 256 + 128 + j] + Part[262144 + (size_t)i * 256 + 128 + j];
    const float y1 = Y1f[(size_t)i * 128 + j];
    const float s  = Sf[(size_t)i * 128 + j];
    const float g  = Gf[(size_t)i * 128 + j];
    const float u  = VU[(size_t)i * 256 + 128 + j];
    const float dA = -dlt[i] * expf(A_log[j]);
    const float bl = -0.1f * y1 + 0.01f * y2;
    const float cq = 0.005f * y3;
    float integ = 0.f;
    #pragma unroll
    for (int k = 0; k < 8; ++k) {
        const float t = c_t[k];
        integ += c_w[k] * (g + t * bl + t * t * cq) * expf(dA * t);
    }
    return u - 0.1f * s + integ;
}

// ---------------------------------------------------------------------------
// ew_mid: post(stage1) -> out[0] ; then pre(stage2) from zt + gelu(out1)
// ---------------------------------------------------------------------------
__global__ __launch_bounds__(128)
void ew_mid(const float* __restrict__ Part, const float* __restrict__ Gf,
            const float* __restrict__ Y1f, const float* __restrict__ Sf,
            const float* __restrict__ zt, const float* __restrict__ dlt1,
            const float* __restrict__ A1,
            const float* __restrict__ rms2, const float* __restrict__ W_B2,
            const float* __restrict__ b_B2, const float* __restrict__ W_dt,
            const float* __restrict__ b_dt, const float* __restrict__ A2,
            const float* __restrict__ m2, const int* __restrict__ act,
            float* __restrict__ VU, unsigned short* __restrict__ VUt,
            float* __restrict__ dlt2, float* __restrict__ out)
{
    const int i = blockIdx.x, j = threadIdx.x;
    __shared__ float xs[HDIM];
    __shared__ float red2[2];

    const float o1 = post_body(i, j, Part, Gf, Y1f, Sf, VU, dlt1, A1);
    out[(size_t)i * 128 + j] = o1;

    const float g3 = o1 * o1 * o1;
    const float gel = 0.5f * o1 * (1.0f + tanhf(0.7978845608028654f * (o1 + 0.044715f * g3)));
    const float x = zt[(size_t)i * 128 + j] + gel;

    pre_body(x, i, j, rms2, W_B2, b_B2, W_dt, b_dt, A2, m2, act,
             VU, VUt, dlt2, xs, red2);
}

// ---------------------------------------------------------------------------
// ew_tail: post(stage2) -> out[1]
// ---------------------------------------------------------------------------
__global__ __launch_bounds__(128)
void ew_tail(const float* __restrict__ Part, const float* __restrict__ Gf,
             const float* __restrict__ Y1f, const float* __restrict__ Sf,
             const float* __restrict__ VU, const float* __restrict__ dlt2,
             const float* __restrict__ A2, float* __restrict__ out)
{
    const int i = blockIdx.x, j = threadIdx.x;
    out[(size_t)i * 128 + j] = post_body(i, j, Part, Gf, Y1f, Sf, VU, dlt2, A2);
}

// ---------------------------------------------------------------------------
extern "C" void kernel_launch(void* const* d_in, const int* in_sizes, int n_in,
                              void* d_out, int out_size, void* d_ws, size_t ws_size,
                              hipStream_t stream)
{
    const float* L      = (const float*)d_in[0];
    const float* dL     = (const float*)d_in[1];
    const float* x_sub  = (const float*)d_in[2];
    const float* m1     = (const float*)d_in[3];
    const float* m2     = (const float*)d_in[4];
    const float* names  = (const float*)d_in[5];
    const float* rms1   = (const float*)d_in[6];
    const float* rms2   = (const float*)d_in[7];
    const float* W_tune = (const float*)d_in[8];
    const float* b_tune = (const float*)d_in[9];
    const float* W_B1   = (const float*)d_in[10];
    const float* b_B1   = (const float*)d_in[11];
    const float* W_B2   = (const float*)d_in[12];
    const float* b_B2   = (const float*)d_in[13];
    const float* W_dt   = (const float*)d_in[14];
    const float* b_dt   = (const float*)d_in[15];
    const float* A1     = (const float*)d_in[16];
    const float* A2     = (const float*)d_in[17];
    const int*   src    = (const int*)d_in[18];
    const int*   dst    = (const int*)d_in[19];
    const int*   act    = (const int*)d_in[20];
    float* out = (float*)d_out;

    // Workspace (~10.5 MB)
    float* ws   = (float*)d_ws;
    float* zt   = ws;                    // 131072
    float* VU   = zt   + 131072;         // 262144  fp32 [V|U]
    float* Gf   = VU   + 262144;         // 131072
    float* Y1f  = Gf   + 131072;         // 131072
    float* Sf   = Y1f  + 131072;         // 131072
    float* dlt1 = Sf   + 131072;         // 1024
    float* dlt2 = dlt1 + 1024;           // 1024
    float* Part = dlt2 + 1024;           // 524288 (GC partials, S=2)
    unsigned short* Lb    = (unsigned short*)(Part + 524288);   // 1048576
    unsigned short* dLb   = Lb    + 1048576;                    // 1048576
    unsigned short* VUt   = dLb   + 1048576;                    // 262144 [V|U]^T
    unsigned short* GTt   = VUt   + 262144;                     // 262144 [G|T]^T
    unsigned short* HY1t  = GTt   + 262144;                     // 262144 [H|Y1]^T

    conv_bf16<<<dim3(2048), dim3(256), 0, stream>>>(L, dL, Lb, dLb);

    ew_head<<<dim3(1024), dim3(128), 0, stream>>>(
        x_sub, names, src, dst, W_tune, b_tune,
        rms1, W_B1, b_B1, W_dt, b_dt, A1, m1, act,
        zt, VU, VUt, dlt1);

    // ---- stage 1 GEMM chain ----
    gemm_ga<<<dim3(4, 16), dim3(256), 0, stream>>>(Lb, dLb, VUt, VU, GTt, Gf);
    gemm_gb<<<dim3(6, 16), dim3(256), 0, stream>>>(Lb, dLb, GTt, HY1t, Y1f, Sf);
    gemm_gc<<<dim3(4, 16, 2), dim3(256), 0, stream>>>(dLb, HY1t, Part);

    ew_mid<<<dim3(1024), dim3(128), 0, stream>>>(
        Part, Gf, Y1f, Sf, zt, dlt1, A1,
        rms2, W_B2, b_B2, W_dt, b_dt, A2, m2, act,
        VU, VUt, dlt2, out);

    // ---- stage 2 GEMM chain ----
    gemm_ga<<<dim3(4, 16), dim3(256), 0, stream>>>(Lb, dLb, VUt, VU, GTt, Gf);
    gemm_gb<<<dim3(6, 16), dim3(256), 0, stream>>>(Lb, dLb, GTt, HY1t, Y1f, Sf);
    gemm_gc<<<dim3(4, 16, 2), dim3(256), 0, stream>>>(dLb, HY1t, Part);

    ew_tail<<<dim3(1024), dim3(128), 0, stream>>>(
        Part, Gf, Y1f, Sf, VU, dlt2, A2, out + 131072);
}